// Round 6
// baseline (442.482 us; speedup 1.0000x reference)
//
#include <hip/hip_runtime.h>
#include <hip/hip_bf16.h>
#include <cstdint>

typedef __hip_bfloat16 bf16;
typedef __attribute__((ext_vector_type(8))) short short8;
typedef __attribute__((ext_vector_type(4))) short short4v;
typedef __attribute__((ext_vector_type(4))) float f32x4;
typedef __attribute__((ext_vector_type(4))) unsigned int uint4v;

__device__ __forceinline__ float bf2f(bf16 v) { return __bfloat162float(v); }
__device__ __forceinline__ bf16  f2bf(float v) { return __float2bfloat16(v); }
__device__ __forceinline__ float rbf(short s) {
  uint32_t u = ((uint32_t)(uint16_t)s) << 16;
  union { uint32_t u; float f; } c; c.u = u; return c.f;
}
__device__ __forceinline__ short wbf(float f) {
  bf16 h = f2bf(f); return *(short*)&h;
}
__device__ __forceinline__ uint32_t pack2(float a, float b) {
  bf16 x = f2bf(a), y = f2bf(b);
  uint16_t xa = *(uint16_t*)&x, ya = *(uint16_t*)&y;
  return (uint32_t)xa | ((uint32_t)ya << 16);
}

// window-order row m -> token index (t*4096 + p)
__device__ __forceinline__ int win_to_token(int m) {
  int n = m >> 8, l = m & 255;
  int t = n >> 4, win = n & 15;
  int wi = win >> 2, wj = win & 3;
  int u = l >> 4, v = l & 15;
  return (t << 12) | ((wi * 16 + u) << 6) | (wj * 16 + v);
}

// ---------------- kernel 1: pool + selector MLP + gumbel mask ----------------
__global__ __launch_bounds__(64) void k_selector(
    const float* __restrict__ x, const float* __restrict__ gu,
    const float* __restrict__ s1w, const float* __restrict__ s1b,
    const float* __restrict__ s2w, const float* __restrict__ s2b,
    const float* __restrict__ s3w, const float* __restrict__ s3b,
    float* __restrict__ f1o, float* __restrict__ f2o, float* __restrict__ f3o,
    float* __restrict__ maskp) {
  int t = blockIdx.x, lane = threadIdx.x;
  int th = t >> 2, tw = t & 3;
  __shared__ float pooled[192];
  __shared__ float f1s[64], f2s[32], f3s[2];
  for (int o = lane; o < 192; o += 64) {
    int ch = o % 3, j = (o / 3) & 7, i = o / 24;
    const float* xp = x + ch * 65536 + (th * 64 + i * 8) * 256 + (tw * 64 + j * 8);
    float s = 0.f;
    for (int a = 0; a < 8; ++a)
      for (int b = 0; b < 8; ++b) s += xp[a * 256 + b];
    pooled[o] = s * (1.0f / 64.0f);
  }
  __syncthreads();
  {
    float s = s1b[lane];
    for (int k = 0; k < 192; ++k) s = fmaf(pooled[k], s1w[k * 64 + lane], s);
    f1o[t * 64 + lane] = s;
    f1s[lane] = fmaxf(s, 0.f);
  }
  __syncthreads();
  if (lane < 32) {
    float s = s2b[lane];
    for (int k = 0; k < 64; ++k) s = fmaf(f1s[k], s2w[k * 32 + lane], s);
    f2o[t * 32 + lane] = s;
    f2s[lane] = fmaxf(s, 0.f);
  }
  __syncthreads();
  if (lane < 2) {
    float s = s3b[lane];
    for (int k = 0; k < 32; ++k) s = fmaf(f2s[k], s3w[k * 2 + lane], s);
    f3o[t * 2 + lane] = s;
    f3s[lane] = s;
  }
  __syncthreads();
  if (lane == 0) {
    float g0 = -logf(-logf(gu[t * 2 + 0] + 1e-10f) + 1e-10f);
    float g1 = -logf(-logf(gu[t * 2 + 1] + 1e-10f) + 1e-10f);
    maskp[t] = (f3s[1] + g1 > f3s[0] + g0) ? 1.0f : 0.0f;
  }
}

// ---------------- pack weights to bf16 Bt[n][k]; qkv permuted to head-padded order ----
// qkv n' = buf*192 + hd*32 + dd (dd>=30 -> 0); also packs permuted qkv bias (f32)
__global__ __launch_bounds__(256) void k_packB(
    const float* __restrict__ qkvw, const float* __restrict__ projw,
    const float* __restrict__ mlp1w, const float* __restrict__ mlp2w,
    const float* __restrict__ upw, const float* __restrict__ qkvb,
    bf16* __restrict__ Bt_qkv, bf16* __restrict__ Bt_proj,
    bf16* __restrict__ Bt_mlp1, bf16* __restrict__ Bt_mlp2,
    bf16* __restrict__ Bt_up, float* __restrict__ biasq) {
  int idx = blockIdx.x * 256 + threadIdx.x;
  const int e0 = 576 * 192, e1 = e0 + 192 * 192, e2 = e1 + 384 * 192,
            e3 = e2 + 192 * 384, e4 = e3 + 64 * 192, e5 = e4 + 576;
  if (idx < e0) {
    int np = idx / 192, k = idx % 192;
    int buf = np / 192; // 0 here, but keep general via colp
    int colp = np % 192;
    buf = np >> 6; buf = np / 192;  // explicit
    int hd = colp >> 5, dd = colp & 31;
    float v = 0.f;
    if (dd < 30 && k < 180) v = qkvw[(size_t)k * 540 + buf * 180 + hd * 30 + dd];
    Bt_qkv[idx] = f2bf(v);
  } else if (idx < e1) {
    int off = idx - e0; int n = off / 192, k = off % 192;
    Bt_proj[off] = f2bf((k < 180 && n < 180) ? projw[(size_t)k * 180 + n] : 0.f);
  } else if (idx < e2) {
    int off = idx - e1; int n = off / 192, k = off % 192;
    Bt_mlp1[off] = f2bf((k < 180 && n < 360) ? mlp1w[(size_t)k * 360 + n] : 0.f);
  } else if (idx < e3) {
    int off = idx - e2; int n = off / 384, k = off % 384;
    Bt_mlp2[off] = f2bf((k < 360 && n < 180) ? mlp2w[(size_t)k * 180 + n] : 0.f);
  } else if (idx < e4) {
    int off = idx - e3; int n = off / 192, k = off % 192;
    Bt_up[off] = f2bf((k < 180 && n < 48) ? upw[(size_t)k * 48 + n] : 0.f);
  } else if (idx < e5) {
    int np = idx - e4;
    int buf = np / 192, colp = np % 192;
    int hd = colp >> 5, dd = colp & 31;
    biasq[np] = (dd < 30) ? qkvb[buf * 180 + hd * 30 + dd] : 0.f;
  }
}

// ---------------- embed (3->180) + LN1 applied, outputs window-major ----------------
__global__ __launch_bounds__(256) void k_embed(
    const float* __restrict__ x, const float* __restrict__ ew,
    const float* __restrict__ eb, const float* __restrict__ g1,
    const float* __restrict__ b1, bf16* __restrict__ tok,
    bf16* __restrict__ Aq) {
  int wrow = blockIdx.x * 4 + (threadIdx.x >> 6);
  int lane = threadIdx.x & 63;
  int token = win_to_token(wrow);
  int t = token >> 12, p = token & 4095;
  int r = p >> 6, c = p & 63;
  int gh = (t >> 2) * 64 + r, gw = (t & 3) * 64 + c;
  float x0 = x[gh * 256 + gw];
  float x1 = x[65536 + gh * 256 + gw];
  float x2 = x[131072 + gh * 256 + gw];
  float v[3];
  float s = 0.f, s2 = 0.f;
#pragma unroll
  for (int i = 0; i < 3; ++i) {
    int e = lane + i * 64;
    float vv = 0.f;
    if (e < 180) {
      vv = eb[e];
      vv = fmaf(x0, ew[e], vv);
      vv = fmaf(x1, ew[180 + e], vv);
      vv = fmaf(x2, ew[360 + e], vv);
      tok[(size_t)wrow * 180 + e] = f2bf(vv);
      s += vv; s2 = fmaf(vv, vv, s2);
    }
    v[i] = vv;
  }
#pragma unroll
  for (int off = 32; off; off >>= 1) { s += __shfl_xor(s, off); s2 += __shfl_xor(s2, off); }
  float mu = s * (1.f / 180.f);
  float rs = rsqrtf(s2 * (1.f / 180.f) - mu * mu + 1e-5f);
#pragma unroll
  for (int i = 0; i < 3; ++i) {
    int e = lane + i * 64;
    if (e < 192) {
      float a = (e < 180) ? ((v[i] - mu) * rs * g1[e] + b1[e]) : 0.f;
      Aq[(size_t)wrow * 192 + e] = f2bf(a);
    }
  }
}

// ---------------- LN2 prep ----------------
__global__ __launch_bounds__(256) void k_ln2prep(
    const bf16* __restrict__ tok, const float* __restrict__ g2,
    const float* __restrict__ b2, bf16* __restrict__ A2) {
  int wrow = blockIdx.x * 4 + (threadIdx.x >> 6);
  int lane = threadIdx.x & 63;
  float v[3];
  float s = 0.f, s2 = 0.f;
#pragma unroll
  for (int i = 0; i < 3; ++i) {
    int e = lane + i * 64;
    float vv = 0.f;
    if (e < 180) {
      vv = bf2f(tok[(size_t)wrow * 180 + e]);
      s += vv; s2 = fmaf(vv, vv, s2);
    }
    v[i] = vv;
  }
#pragma unroll
  for (int off = 32; off; off >>= 1) { s += __shfl_xor(s, off); s2 += __shfl_xor(s2, off); }
  float mu = s * (1.f / 180.f);
  float rs = rsqrtf(s2 * (1.f / 180.f) - mu * mu + 1e-5f);
#pragma unroll
  for (int i = 0; i < 3; ++i) {
    int e = lane + i * 64;
    if (e < 192) {
      float a = (e < 180) ? ((v[i] - mu) * rs * g2[e] + b2[e]) : 0.f;
      A2[(size_t)wrow * 192 + e] = f2bf(a);
    }
  }
}

// ---------------- MFMA GEMM, n-loop in-block, LDS-staged coalesced epilogue ----------
// EPI: 0=plain store, 1=accum into C (8B RMW), 2=gelu store, 3=QKV (QK rows + V^T)
// MT=64: 4 waves x 16 rows; NSPLIT: n-tile interleave across blockIdx.y
template <int KPAD, int EPI, int NSPLIT>
__global__ __launch_bounds__(256) void k_gemm_nloop(
    const bf16* __restrict__ A, int ldA,
    const bf16* __restrict__ Bt, const float* __restrict__ bias,
    bf16* __restrict__ Cp, int ldC, int N, int NT,
    bf16* __restrict__ Qo, bf16* __restrict__ Ko, bf16* __restrict__ Vo) {
  constexpr int MT = 64;
  constexpr int KS = KPAD / 32;
  __shared__ bf16 Cs[MT][80];  // 160B row stride: 16B-aligned rows
  const int tid = threadIdx.x;
  const int w = tid >> 6, l = tid & 63;
  const int lr = l & 15, lk = l >> 4;
  const int m0 = blockIdx.x * MT;
  short8 fa[KS];
  const bf16* Abase = A + (size_t)(m0 + w * 16 + lr) * ldA + lk * 8;
#pragma unroll
  for (int ks = 0; ks < KS; ++ks)
    fa[ks] = *(const short8*)(Abase + ks * 32);
  for (int nt = blockIdx.y; nt < NT; nt += NSPLIT) {
    const int n0 = nt * 64;
    const bf16* Brow = Bt + (size_t)(n0 + lr) * KPAD + lk * 8;
    f32x4 acc[4];
#pragma unroll
    for (int j = 0; j < 4; ++j) acc[j] = (f32x4){0.f, 0.f, 0.f, 0.f};
#pragma unroll
    for (int ks = 0; ks < KS; ++ks) {
      short8 fb[4];
#pragma unroll
      for (int j = 0; j < 4; ++j)
        fb[j] = *(const short8*)(Brow + (size_t)j * 16 * KPAD + ks * 32);
#pragma unroll
      for (int j = 0; j < 4; ++j)
        acc[j] = __builtin_amdgcn_mfma_f32_16x16x32_bf16(fa[ks], fb[j], acc[j], 0, 0, 0);
    }
    __syncthreads();  // previous tile's writers done
    // stage fragments -> LDS (with bias / gelu / zero-pad)
    {
      int rbase = w * 16 + lk * 4;
#pragma unroll
      for (int j = 0; j < 4; ++j) {
        int n = n0 + j * 16 + lr;
#pragma unroll
        for (int q = 0; q < 4; ++q) {
          float vv = 0.f;
          if (EPI == 3) {
            vv = acc[j][q] + bias[n];
          } else if (n < N) {
            vv = acc[j][q] + bias[n];
            if (EPI == 2) {
              float u = 0.7978845608028654f * (vv + 0.044715f * vv * vv * vv);
              vv = vv / (1.f + __expf(-2.f * u));
            }
          }
          Cs[rbase + q][j * 16 + lr] = f2bf(vv);
        }
      }
    }
    __syncthreads();
    // coalesced writers
    if (EPI == 3) {
      if (n0 < 384) {  // Q or K rows, [m][192]
        bf16* dst = (n0 < 192) ? (Qo + n0) : (Ko + (n0 - 192));
#pragma unroll
        for (int it = 0; it < 2; ++it) {
          int flat = tid + it * 256;
          int m = flat >> 3, c = flat & 7;
          *(uint4v*)(dst + (size_t)(m0 + m) * 192 + c * 8) = *(const uint4v*)&Cs[m][c * 8];
        }
      } else {  // V transpose: Vo[d][65536]
        int d0 = n0 - 384;
#pragma unroll
        for (int it = 0; it < 2; ++it) {
          int flat = tid + it * 256;
          int c = flat >> 3, mc = flat & 7;
          short8 vv;
#pragma unroll
          for (int e = 0; e < 8; ++e) vv[e] = *(const short*)&Cs[mc * 8 + e][c];
          *(short8*)(Vo + (size_t)(d0 + c) * 65536 + m0 + mc * 8) = vv;
        }
      }
    } else if (EPI == 1) {  // accum: 8B RMW
#pragma unroll
      for (int it = 0; it < 4; ++it) {
        int flat = tid + it * 256;
        int m = flat >> 4, c = flat & 15;
        int nn = n0 + c * 4;
        if (nn < ldC) {
          bf16* dst = Cp + (size_t)(m0 + m) * ldC + nn;
          short4v o = *(const short4v*)dst;
          short4v nv;
#pragma unroll
          for (int e = 0; e < 4; ++e)
            nv[e] = wbf(rbf(o[e]) + rbf(*(const short*)&Cs[m][c * 4 + e]));
          *(short4v*)dst = nv;
        }
      }
    } else {  // plain / gelu: 16B row writes
#pragma unroll
      for (int it = 0; it < 2; ++it) {
        int flat = tid + it * 256;
        int m = flat >> 3, c = flat & 7;
        int nn = n0 + c * 8;
        if (nn < ldC)
          *(uint4v*)(Cp + (size_t)(m0 + m) * ldC + nn) = *(const uint4v*)&Cs[m][c * 8];
      }
    }
  }
}

// ---------------- MFMA attention: block = (window, head), 4 waves ----------------
__global__ __launch_bounds__(256) void k_attn_mfma(
    const bf16* __restrict__ Qp, const bf16* __restrict__ Kp,
    const bf16* __restrict__ Vt, bf16* __restrict__ av) {
  const int blk = blockIdx.x;
  const int win = blk / 6, hd = blk % 6;
  const int tid = threadIdx.x;
  const int w = tid >> 6, l = tid & 63;
  const int lr = l & 15, lk = l >> 4;
  const float scale = 0.18257418583505536f;  // 1/sqrt(30)

  __shared__ bf16 Ks[256][40];
  __shared__ bf16 Vs[32][264];
  __shared__ bf16 Ps[4][16][264];

  {
    const bf16* src = Kp + (size_t)(win * 256 + tid) * 192 + hd * 32;
#pragma unroll
    for (int c = 0; c < 4; ++c)
      *(short8*)&Ks[tid][c * 8] = *(const short8*)(src + c * 8);
  }
  {
    int d = tid >> 3, ck = tid & 7;
    const bf16* src = Vt + (size_t)(hd * 32 + d) * 65536 + win * 256 + ck * 32;
#pragma unroll
    for (int c = 0; c < 4; ++c)
      *(short8*)&Vs[d][ck * 32 + c * 8] = *(const short8*)(src + c * 8);
  }
  __syncthreads();

  for (int qt = 0; qt < 4; ++qt) {
    const int qbase = qt * 64 + w * 16;
    short8 fq = *(const short8*)(Qp + (size_t)(win * 256 + qbase + lr) * 192 + hd * 32 + lk * 8);
    f32x4 accS[16];
#pragma unroll
    for (int kt = 0; kt < 16; ++kt) {
      short8 fk = *(const short8*)(&Ks[kt * 16 + lr][lk * 8]);
      accS[kt] = __builtin_amdgcn_mfma_f32_16x16x32_bf16(
          fk, fq, (f32x4){0.f, 0.f, 0.f, 0.f}, 0, 0, 0);
    }
    float mraw = -1e30f;
#pragma unroll
    for (int kt = 0; kt < 16; ++kt)
#pragma unroll
      for (int r = 0; r < 4; ++r) mraw = fmaxf(mraw, accS[kt][r]);
    mraw = fmaxf(mraw, __shfl_xor(mraw, 16));
    mraw = fmaxf(mraw, __shfl_xor(mraw, 32));
    const float mc = mraw * scale;
    float lsum = 0.f;
#pragma unroll
    for (int kt = 0; kt < 16; ++kt) {
      float p0 = __expf(fmaf(accS[kt][0], scale, -mc));
      float p1 = __expf(fmaf(accS[kt][1], scale, -mc));
      float p2 = __expf(fmaf(accS[kt][2], scale, -mc));
      float p3 = __expf(fmaf(accS[kt][3], scale, -mc));
      lsum += (p0 + p1) + (p2 + p3);
      uint32_t d0 = pack2(p0, p1), d1 = pack2(p2, p3);
      *(uint32_t*)&Ps[w][lr][kt * 16 + lk * 4]     = d0;
      *(uint32_t*)&Ps[w][lr][kt * 16 + lk * 4 + 2] = d1;
    }
    lsum += __shfl_xor(lsum, 16);
    lsum += __shfl_xor(lsum, 32);
    __syncthreads();
    f32x4 accO0 = (f32x4){0.f, 0.f, 0.f, 0.f};
    f32x4 accO1 = (f32x4){0.f, 0.f, 0.f, 0.f};
#pragma unroll
    for (int ks = 0; ks < 8; ++ks) {
      short8 fp = *(const short8*)(&Ps[w][lr][ks * 32 + lk * 8]);
      short8 fv0 = *(const short8*)(&Vs[lr][ks * 32 + lk * 8]);
      short8 fv1 = *(const short8*)(&Vs[16 + lr][ks * 32 + lk * 8]);
      accO0 = __builtin_amdgcn_mfma_f32_16x16x32_bf16(fp, fv0, accO0, 0, 0, 0);
      accO1 = __builtin_amdgcn_mfma_f32_16x16x32_bf16(fp, fv1, accO1, 0, 0, 0);
    }
    float invl = 1.f / lsum;
#pragma unroll
    for (int r = 0; r < 4; ++r) {
      float inv_r = __shfl(invl, lk * 4 + r);
      int row = win * 256 + qbase + lk * 4 + r;
      int d0 = lr, d1 = 16 + lr;
      if (d0 < 30) av[(size_t)row * 192 + hd * 30 + d0] = f2bf(accO0[r] * inv_r);
      if (d1 < 30) av[(size_t)row * 192 + hd * 30 + d1] = f2bf(accO1[r] * inv_r);
      if (hd == 0 && lr < 12) av[(size_t)row * 192 + 180 + lr] = f2bf(0.f);
    }
    __syncthreads();
  }
}

// ---------------- bicubic weights (jax Keys a=-0.5, half-pixel, edge renorm) ----------------
__device__ const float c_cubw[4][4] = {
    {-0.0439453125f, 0.3896484375f, 0.7275390625f, -0.0732421875f},
    {-0.0068359375f, 0.0908203125f, 0.9638671875f, -0.0478515625f},
    {-0.0478515625f, 0.9638671875f, 0.0908203125f, -0.0068359375f},
    {-0.0732421875f, 0.7275390625f, 0.3896484375f, -0.0439453125f},
};

__device__ __forceinline__ void cubw(int r, int ph, float* w, int& base) {
  base = r + ((ph < 2) ? -2 : -1);
  float sum = 0.f;
#pragma unroll
  for (int i = 0; i < 4; ++i) {
    int idx = base + i;
    float wi = (idx >= 0 && idx < 64) ? c_cubw[ph][i] : 0.f;
    w[i] = wi; sum += wi;
  }
  float inv = 1.f / sum;
#pragma unroll
  for (int i = 0; i < 4; ++i) w[i] *= inv;
}

// ---------------- blend: pixel-shuffle of up + bicubic + mask blend ----------------
__global__ __launch_bounds__(256) void k_blend(
    const bf16* __restrict__ up, const float* __restrict__ x,
    const float* __restrict__ maskp, float* __restrict__ sr) {
  int idx = blockIdx.x * 256 + threadIdx.x;
  int ch = idx >> 20;
  int rem = idx & 1048575;
  int gR = rem >> 10, gC = rem & 1023;
  int th = gR >> 8, tw = gC >> 8;
  int t = th * 4 + tw;
  int R = gR & 255, C = gC & 255;
  int r = R >> 2, a = R & 3, c = C >> 2, b = C & 3;
  float m = maskp[t];
  float outv;
  if (m > 0.5f) {
    int wi = r >> 4, u = r & 15, wj = c >> 4, v = c & 15;
    int wrow = (t * 16 + wi * 4 + wj) * 256 + u * 16 + v;
    outv = bf2f(up[(size_t)wrow * 48 + a * 12 + b * 3 + ch]);
  } else {
    float wy[4], wx[4];
    int yb, xb;
    cubw(r, a, wy, yb);
    cubw(c, b, wx, xb);
    const float* xc = x + ch * 65536;
    float neg = 0.f;
#pragma unroll
    for (int i = 0; i < 4; ++i) {
      int yi = yb + i;
      if (yi < 0 || yi > 63) continue;
      float rowsum = 0.f;
#pragma unroll
      for (int j = 0; j < 4; ++j) {
        int xj = xb + j;
        if (xj < 0 || xj > 63) continue;
        rowsum = fmaf(wx[j], xc[(th * 64 + yi) * 256 + tw * 64 + xj], rowsum);
      }
      neg = fmaf(wy[i], rowsum, neg);
    }
    outv = neg;
  }
  sr[idx] = outv;
}

// ---------------- launcher ----------------
extern "C" void kernel_launch(void* const* d_in, const int* in_sizes, int n_in,
                              void* d_out, int out_size, void* d_ws, size_t ws_size,
                              hipStream_t stream) {
  const float* x     = (const float*)d_in[0];
  const float* gu    = (const float*)d_in[1];
  const float* s1w   = (const float*)d_in[2];
  const float* s1b   = (const float*)d_in[3];
  const float* s2w   = (const float*)d_in[4];
  const float* s2b   = (const float*)d_in[5];
  const float* s3w   = (const float*)d_in[6];
  const float* s3b   = (const float*)d_in[7];
  const float* ew    = (const float*)d_in[8];
  const float* ebias = (const float*)d_in[9];
  const float* ln1g  = (const float*)d_in[10];
  const float* ln1b  = (const float*)d_in[11];
  const float* qkvw  = (const float*)d_in[12];
  const float* qkvb  = (const float*)d_in[13];
  const float* projw = (const float*)d_in[14];
  const float* projb = (const float*)d_in[15];
  const float* ln2g  = (const float*)d_in[16];
  const float* ln2b  = (const float*)d_in[17];
  const float* mlp1w = (const float*)d_in[18];
  const float* mlp1b = (const float*)d_in[19];
  const float* mlp2w = (const float*)d_in[20];
  const float* mlp2b = (const float*)d_in[21];
  const float* upw   = (const float*)d_in[22];
  const float* upb   = (const float*)d_in[23];

  float* out = (float*)d_out;
  float* sr  = out;                 // 3*1024*1024
  float* f3o = out + 3145728;       // 16*2
  float* f2o = f3o + 32;            // 16*32
  float* f1o = f2o + 512;           // 16*64

  char* ws = (char*)d_ws;
  bf16* tok  = (bf16*)(ws);                   // 65536*180 = 23,592,960 B
  bf16* ABuf = (bf16*)(ws + 23592960);        // 65536*192 = 25,165,824 B
  bf16* Qp   = (bf16*)(ws + 48758784);        // 65536*192
  bf16* Kp   = (bf16*)(ws + 73924608);        // 65536*192
  bf16* Vt   = (bf16*)(ws + 99090432);        // 192*65536
  bf16* mid  = Qp;                            // reuse Qp+Kp: 65536*384
  float* maskp   = (float*)(ws + 124256256);  // 64 B
  bf16* Bt_qkv  = (bf16*)(ws + 124256320);    // 576*192*2 = 221,184
  bf16* Bt_proj = (bf16*)(ws + 124477504);    // 192*192*2 = 73,728
  bf16* Bt_mlp1 = (bf16*)(ws + 124551232);    // 384*192*2 = 147,456
  bf16* Bt_mlp2 = (bf16*)(ws + 124698688);    // 192*384*2 = 147,456
  bf16* Bt_up   = (bf16*)(ws + 124846144);    // 64*192*2  = 24,576
  float* biasq  = (float*)(ws + 124870720);   // 576*4 = 2,304
  bf16* up      = (bf16*)(ws + 124873088);    // 65536*48*2 = 6,291,456

  k_selector<<<16, 64, 0, stream>>>(x, gu, s1w, s1b, s2w, s2b, s3w, s3b, f1o, f2o, f3o, maskp);
  k_packB<<<1203, 256, 0, stream>>>(qkvw, projw, mlp1w, mlp2w, upw, qkvb,
                                    Bt_qkv, Bt_proj, Bt_mlp1, Bt_mlp2, Bt_up, biasq);
  k_embed<<<16384, 256, 0, stream>>>(x, ew, ebias, ln1g, ln1b, tok, ABuf);
  // Q/K/V = LN1(tok) @ qkv_w + qkv_b (permuted head-padded output; pads exact 0)
  k_gemm_nloop<192, 3, 2><<<dim3(1024, 2), 256, 0, stream>>>(
      ABuf, 192, Bt_qkv, biasq, nullptr, 0, 576, 9, Qp, Kp, Vt);
  k_attn_mfma<<<1536, 256, 0, stream>>>(Qp, Kp, Vt, ABuf);
  // tok += av @ proj_w + proj_b
  k_gemm_nloop<192, 1, 1><<<dim3(1024, 1), 256, 0, stream>>>(
      ABuf, 192, Bt_proj, projb, tok, 180, 180, 3, nullptr, nullptr, nullptr);
  k_ln2prep<<<16384, 256, 0, stream>>>(tok, ln2g, ln2b, ABuf);
  // mid = gelu(LN2(tok) @ mlp1_w + mlp1_b), zero-padded to 384 cols
  k_gemm_nloop<192, 2, 2><<<dim3(1024, 2), 256, 0, stream>>>(
      ABuf, 192, Bt_mlp1, mlp1b, mid, 384, 360, 6, nullptr, nullptr, nullptr);
  // tok += mid @ mlp2_w + mlp2_b
  k_gemm_nloop<384, 1, 1><<<dim3(1024, 1), 256, 0, stream>>>(
      mid, 384, Bt_mlp2, mlp2b, tok, 180, 180, 3, nullptr, nullptr, nullptr);
  // up = tok @ up_w + up_b
  k_gemm_nloop<192, 0, 1><<<dim3(1024, 1), 256, 0, stream>>>(
      tok, 180, Bt_up, upb, up, 48, 48, 1, nullptr, nullptr, nullptr);
  k_blend<<<12288, 256, 0, stream>>>(up, x, maskp, sr);
}

// Round 7
// 366.229 us; speedup vs baseline: 1.2082x; 1.2082x over previous
//
#include <hip/hip_runtime.h>
#include <hip/hip_bf16.h>
#include <cstdint>

typedef __hip_bfloat16 bf16;
typedef __attribute__((ext_vector_type(8))) short short8;
typedef __attribute__((ext_vector_type(4))) short short4v;
typedef __attribute__((ext_vector_type(4))) float f32x4;
typedef __attribute__((ext_vector_type(2))) unsigned int uint2v;

__device__ __forceinline__ float bf2f(bf16 v) { return __bfloat162float(v); }
__device__ __forceinline__ bf16  f2bf(float v) { return __float2bfloat16(v); }
__device__ __forceinline__ float rbf(short s) {
  union { uint32_t u; float f; } c; c.u = ((uint32_t)(uint16_t)s) << 16; return c.f;
}
__device__ __forceinline__ uint32_t pack2(float a, float b) {
  bf16 x = f2bf(a), y = f2bf(b);
  return (uint32_t)(*(uint16_t*)&x) | ((uint32_t)(*(uint16_t*)&y) << 16);
}
__device__ __forceinline__ uint2v pack4(float a, float b, float c, float d) {
  uint2v r; r[0] = pack2(a, b); r[1] = pack2(c, d); return r;
}

// window-order row m -> token index (t*4096 + p)
__device__ __forceinline__ int win_to_token(int m) {
  int n = m >> 8, l = m & 255;
  int t = n >> 4, win = n & 15;
  int wi = win >> 2, wj = win & 3;
  int u = l >> 4, v = l & 15;
  return (t << 12) | ((wi * 16 + u) << 6) | (wj * 16 + v);
}

// ---------------- kernel 1: pool + selector MLP + gumbel mask ----------------
__global__ __launch_bounds__(64) void k_selector(
    const float* __restrict__ x, const float* __restrict__ gu,
    const float* __restrict__ s1w, const float* __restrict__ s1b,
    const float* __restrict__ s2w, const float* __restrict__ s2b,
    const float* __restrict__ s3w, const float* __restrict__ s3b,
    float* __restrict__ f1o, float* __restrict__ f2o, float* __restrict__ f3o,
    float* __restrict__ maskp) {
  int t = blockIdx.x, lane = threadIdx.x;
  int th = t >> 2, tw = t & 3;
  __shared__ float pooled[192];
  __shared__ float f1s[64], f2s[32], f3s[2];
  for (int o = lane; o < 192; o += 64) {
    int ch = o % 3, j = (o / 3) & 7, i = o / 24;
    const float* xp = x + ch * 65536 + (th * 64 + i * 8) * 256 + (tw * 64 + j * 8);
    float s = 0.f;
    for (int a = 0; a < 8; ++a)
      for (int b = 0; b < 8; ++b) s += xp[a * 256 + b];
    pooled[o] = s * (1.0f / 64.0f);
  }
  __syncthreads();
  {
    float s = s1b[lane];
    for (int k = 0; k < 192; ++k) s = fmaf(pooled[k], s1w[k * 64 + lane], s);
    f1o[t * 64 + lane] = s;
    f1s[lane] = fmaxf(s, 0.f);
  }
  __syncthreads();
  if (lane < 32) {
    float s = s2b[lane];
    for (int k = 0; k < 64; ++k) s = fmaf(f1s[k], s2w[k * 32 + lane], s);
    f2o[t * 32 + lane] = s;
    f2s[lane] = fmaxf(s, 0.f);
  }
  __syncthreads();
  if (lane < 2) {
    float s = s3b[lane];
    for (int k = 0; k < 32; ++k) s = fmaf(f2s[k], s3w[k * 2 + lane], s);
    f3o[t * 2 + lane] = s;
    f3s[lane] = s;
  }
  __syncthreads();
  if (lane == 0) {
    float g0 = -logf(-logf(gu[t * 2 + 0] + 1e-10f) + 1e-10f);
    float g1 = -logf(-logf(gu[t * 2 + 1] + 1e-10f) + 1e-10f);
    maskp[t] = (f3s[1] + g1 > f3s[0] + g0) ? 1.0f : 0.0f;
  }
}

// ---------------- pack weights to bf16 Bt[n][k] ----------------
// Bt_qkv: n' = buf*192 + hd*32 + dd (pads zero). Bt_proj: k' = hd*32 + dd (pads zero).
__global__ __launch_bounds__(256) void k_packB(
    const float* __restrict__ qkvw, const float* __restrict__ projw,
    const float* __restrict__ mlp1w, const float* __restrict__ mlp2w,
    const float* __restrict__ upw, const float* __restrict__ qkvb,
    bf16* __restrict__ Bt_qkv, bf16* __restrict__ Bt_proj,
    bf16* __restrict__ Bt_mlp1, bf16* __restrict__ Bt_mlp2,
    bf16* __restrict__ Bt_up, float* __restrict__ biasq) {
  int idx = blockIdx.x * 256 + threadIdx.x;
  const int e0 = 576 * 192, e1 = e0 + 192 * 192, e2 = e1 + 384 * 192,
            e3 = e2 + 192 * 384, e4 = e3 + 64 * 192, e5 = e4 + 576;
  if (idx < e0) {
    int np = idx / 192, k = idx % 192;
    int buf = np / 192, colp = np % 192;
    int hd = colp >> 5, dd = colp & 31;
    float v = 0.f;
    if (dd < 30 && k < 180) v = qkvw[(size_t)k * 540 + buf * 180 + hd * 30 + dd];
    Bt_qkv[idx] = f2bf(v);
  } else if (idx < e1) {
    int off = idx - e0; int n = off / 192, kp = off % 192;
    int hd = kp >> 5, dd = kp & 31;
    float v = (dd < 30 && n < 180) ? projw[(size_t)(hd * 30 + dd) * 180 + n] : 0.f;
    Bt_proj[off] = f2bf(v);
  } else if (idx < e2) {
    int off = idx - e1; int n = off / 192, k = off % 192;
    Bt_mlp1[off] = f2bf((k < 180 && n < 360) ? mlp1w[(size_t)k * 360 + n] : 0.f);
  } else if (idx < e3) {
    int off = idx - e2; int n = off / 384, k = off % 384;
    Bt_mlp2[off] = f2bf((k < 360 && n < 180) ? mlp2w[(size_t)k * 180 + n] : 0.f);
  } else if (idx < e4) {
    int off = idx - e3; int n = off / 192, k = off % 192;
    Bt_up[off] = f2bf((k < 180 && n < 48) ? upw[(size_t)k * 48 + n] : 0.f);
  } else if (idx < e5) {
    int np = idx - e4;
    int buf = np / 192, colp = np % 192;
    int hd = colp >> 5, dd = colp & 31;
    biasq[np] = (dd < 30) ? qkvb[buf * 180 + hd * 30 + dd] : 0.f;
  }
}

// ---------------- embed (3->180) + LN1 applied, outputs window-major ----------------
__global__ __launch_bounds__(256) void k_embed(
    const float* __restrict__ x, const float* __restrict__ ew,
    const float* __restrict__ eb, const float* __restrict__ g1,
    const float* __restrict__ b1, bf16* __restrict__ tok,
    bf16* __restrict__ Aq) {
  int wrow = blockIdx.x * 4 + (threadIdx.x >> 6);
  int lane = threadIdx.x & 63;
  int token = win_to_token(wrow);
  int t = token >> 12, p = token & 4095;
  int r = p >> 6, c = p & 63;
  int gh = (t >> 2) * 64 + r, gw = (t & 3) * 64 + c;
  float x0 = x[gh * 256 + gw];
  float x1 = x[65536 + gh * 256 + gw];
  float x2 = x[131072 + gh * 256 + gw];
  float v[3];
  float s = 0.f, s2 = 0.f;
#pragma unroll
  for (int i = 0; i < 3; ++i) {
    int e = lane + i * 64;
    float vv = 0.f;
    if (e < 180) {
      vv = eb[e];
      vv = fmaf(x0, ew[e], vv);
      vv = fmaf(x1, ew[180 + e], vv);
      vv = fmaf(x2, ew[360 + e], vv);
      tok[(size_t)wrow * 180 + e] = f2bf(vv);
      s += vv; s2 = fmaf(vv, vv, s2);
    }
    v[i] = vv;
  }
#pragma unroll
  for (int off = 32; off; off >>= 1) { s += __shfl_xor(s, off); s2 += __shfl_xor(s2, off); }
  float mu = s * (1.f / 180.f);
  float rs = rsqrtf(s2 * (1.f / 180.f) - mu * mu + 1e-5f);
#pragma unroll
  for (int i = 0; i < 3; ++i) {
    int e = lane + i * 64;
    if (e < 192) {
      float a = (e < 180) ? ((v[i] - mu) * rs * g1[e] + b1[e]) : 0.f;
      Aq[(size_t)wrow * 192 + e] = f2bf(a);
    }
  }
}

// ---------------- qkv GEMM: swapped operands, 8B coalesced row stores ----------------
// A[65536][192] -> Qp/Kp/Vp[65536][192] (head-padded cols, pads exact 0)
__global__ __launch_bounds__(256) void k_qkv(
    const bf16* __restrict__ A, const bf16* __restrict__ Bt,
    const float* __restrict__ biasq, bf16* __restrict__ Qp,
    bf16* __restrict__ Kp, bf16* __restrict__ Vp) {
  const int tid = threadIdx.x;
  const int w = tid >> 6, l = tid & 63;
  const int lr = l & 15, lk = l >> 4;
  const int row_g = blockIdx.x * 64 + w * 16 + lr;
  short8 fa[6];
  const bf16* Ab = A + (size_t)row_g * 192 + lk * 8;
#pragma unroll
  for (int ks = 0; ks < 6; ++ks) fa[ks] = *(const short8*)(Ab + ks * 32);
#pragma unroll
  for (int nt = 0; nt < 9; ++nt) {
    const bf16* Bb = Bt + (size_t)nt * 64 * 192;
    f32x4 acc[4];
#pragma unroll
    for (int j = 0; j < 4; ++j) acc[j] = (f32x4){0.f, 0.f, 0.f, 0.f};
#pragma unroll
    for (int ks = 0; ks < 6; ++ks) {
      short8 fb[4];
#pragma unroll
      for (int j = 0; j < 4; ++j)
        fb[j] = *(const short8*)(Bb + (size_t)(j * 16 + lr) * 192 + ks * 32 + lk * 8);
#pragma unroll
      for (int j = 0; j < 4; ++j)
        acc[j] = __builtin_amdgcn_mfma_f32_16x16x32_bf16(fb[j], fa[ks], acc[j], 0, 0, 0);
    }
    bf16* dst = (nt < 3) ? Qp : (nt < 6) ? Kp : Vp;
    int c0 = (nt % 3) * 64;
#pragma unroll
    for (int j = 0; j < 4; ++j) {
      int np = nt * 64 + j * 16 + lk * 4;
      f32x4 bv = *(const f32x4*)&biasq[np];
      *(uint2v*)(dst + (size_t)row_g * 192 + c0 + j * 16 + lk * 4) =
          pack4(acc[j][0] + bv[0], acc[j][1] + bv[1], acc[j][2] + bv[2], acc[j][3] + bv[3]);
    }
  }
}

// ---------------- MFMA attention: block = (window, head), swapped PV ----------------
__global__ __launch_bounds__(256) void k_attn2(
    const bf16* __restrict__ Qp, const bf16* __restrict__ Kp,
    const bf16* __restrict__ Vp, bf16* __restrict__ av) {
  const int blk = blockIdx.x;
  const int win = blk / 6, hd = blk % 6;
  const int tid = threadIdx.x;
  const int w = tid >> 6, l = tid & 63;
  const int lr = l & 15, lk = l >> 4;
  const float scale = 0.18257418583505536f;  // 1/sqrt(30)

  __shared__ bf16 Ks[256][40];
  __shared__ bf16 Vs[32][264];
  __shared__ bf16 Ps[4][16][264];

  {  // stage K rows
    const bf16* src = Kp + (size_t)(win * 256 + tid) * 192 + hd * 32;
#pragma unroll
    for (int c = 0; c < 4; ++c)
      *(short8*)&Ks[tid][c * 8] = *(const short8*)(src + c * 8);
  }
  {  // stage V rows -> transposed Vs[d][key]
    const bf16* src = Vp + (size_t)(win * 256 + tid) * 192 + hd * 32;
    short8 vv[4];
#pragma unroll
    for (int c = 0; c < 4; ++c) vv[c] = *(const short8*)(src + c * 8);
#pragma unroll
    for (int c = 0; c < 4; ++c)
#pragma unroll
      for (int e = 0; e < 8; ++e)
        *(short*)&Vs[c * 8 + e][tid] = vv[c][e];
  }
  __syncthreads();

  for (int qt = 0; qt < 4; ++qt) {
    const int qbase = qt * 64 + w * 16;
    short8 fq = *(const short8*)(Qp + (size_t)(win * 256 + qbase + lr) * 192 + hd * 32 + lk * 8);
    f32x4 accS[16];
#pragma unroll
    for (int kt = 0; kt < 16; ++kt) {
      short8 fk = *(const short8*)(&Ks[kt * 16 + lr][lk * 8]);
      accS[kt] = __builtin_amdgcn_mfma_f32_16x16x32_bf16(
          fk, fq, (f32x4){0.f, 0.f, 0.f, 0.f}, 0, 0, 0);
    }
    float mraw = -1e30f;
#pragma unroll
    for (int kt = 0; kt < 16; ++kt)
#pragma unroll
      for (int r = 0; r < 4; ++r) mraw = fmaxf(mraw, accS[kt][r]);
    mraw = fmaxf(mraw, __shfl_xor(mraw, 16));
    mraw = fmaxf(mraw, __shfl_xor(mraw, 32));
    const float mc = mraw * scale;
    float lsum = 0.f;
#pragma unroll
    for (int kt = 0; kt < 16; ++kt) {
      float p0 = __expf(fmaf(accS[kt][0], scale, -mc));
      float p1 = __expf(fmaf(accS[kt][1], scale, -mc));
      float p2 = __expf(fmaf(accS[kt][2], scale, -mc));
      float p3 = __expf(fmaf(accS[kt][3], scale, -mc));
      lsum += (p0 + p1) + (p2 + p3);
      *(uint32_t*)&Ps[w][lr][kt * 16 + lk * 4]     = pack2(p0, p1);
      *(uint32_t*)&Ps[w][lr][kt * 16 + lk * 4 + 2] = pack2(p2, p3);
    }
    lsum += __shfl_xor(lsum, 16);
    lsum += __shfl_xor(lsum, 32);
    __syncthreads();
    f32x4 accO0 = (f32x4){0.f, 0.f, 0.f, 0.f};
    f32x4 accO1 = (f32x4){0.f, 0.f, 0.f, 0.f};
#pragma unroll
    for (int ks = 0; ks < 8; ++ks) {
      short8 fp  = *(const short8*)(&Ps[w][lr][ks * 32 + lk * 8]);
      short8 fv0 = *(const short8*)(&Vs[lr][ks * 32 + lk * 8]);
      short8 fv1 = *(const short8*)(&Vs[16 + lr][ks * 32 + lk * 8]);
      accO0 = __builtin_amdgcn_mfma_f32_16x16x32_bf16(fv0, fp, accO0, 0, 0, 0);
      accO1 = __builtin_amdgcn_mfma_f32_16x16x32_bf16(fv1, fp, accO1, 0, 0, 0);
    }
    // lane lr = query; regs = d = j*16 + lk*4 + r
    float invl = 1.f / lsum;
    bf16* avrow = av + (size_t)(win * 256 + qbase + lr) * 192 + hd * 32;
    *(uint2v*)(avrow + lk * 4) =
        pack4(accO0[0] * invl, accO0[1] * invl, accO0[2] * invl, accO0[3] * invl);
    *(uint2v*)(avrow + 16 + lk * 4) =
        pack4(accO1[0] * invl, accO1[1] * invl, accO1[2] * invl, accO1[3] * invl);
    __syncthreads();
  }
}

// ---------------- fused post-attn: proj+res -> LN2 -> mlp1(gelu) -> mlp2+res -> up ----
__global__ __launch_bounds__(256) void k_post(
    const bf16* __restrict__ av, const bf16* __restrict__ tok,
    const bf16* __restrict__ Btp, const float* __restrict__ pb,
    const float* __restrict__ g2, const float* __restrict__ b2,
    const bf16* __restrict__ Bt1, const float* __restrict__ b1m,
    const bf16* __restrict__ Bt2, const float* __restrict__ b2m,
    const bf16* __restrict__ Btu, const float* __restrict__ bu,
    bf16* __restrict__ up) {
  __shared__ bf16 T2[64 * 200];   // tok2 (then tok3 in place); cols 180..191 zero
  __shared__ bf16 Mm[64 * 392];   // mid (gelu), cols 360..383 zero
  __shared__ bf16 BsH[64 * 392];  // B-tile staging; transiently reused as H2 (LN2 out)
  const int tid = threadIdx.x;
  const int w = tid >> 6, l = tid & 63;
  const int lr = l & 15, lk = l >> 4;
  const int row_l = w * 16 + lr;
  const int row_g = blockIdx.x * 64 + row_l;

  // av A-frags (K=192)
  short8 fa[6];
  {
    const bf16* ab = av + (size_t)row_g * 192 + lk * 8;
#pragma unroll
    for (int ks = 0; ks < 6; ++ks) fa[ks] = *(const short8*)(ab + ks * 32);
  }

  // ======= proj (NT=3, N=180) + bias + tok residual -> T2 =======
#pragma unroll
  for (int nt = 0; nt < 3; ++nt) {
    __syncthreads();
    for (int c = tid; c < 1536; c += 256) {  // stage B tile 64x192, stride 200
      int n = c / 24, k8 = c % 24;
      *(short8*)&BsH[n * 200 + k8 * 8] =
          *(const short8*)(Btp + (size_t)(nt * 64 + n) * 192 + k8 * 8);
    }
    __syncthreads();
    f32x4 acc[4];
#pragma unroll
    for (int j = 0; j < 4; ++j) acc[j] = (f32x4){0.f, 0.f, 0.f, 0.f};
#pragma unroll
    for (int ks = 0; ks < 6; ++ks) {
      short8 fb[4];
#pragma unroll
      for (int j = 0; j < 4; ++j)
        fb[j] = *(const short8*)&BsH[(j * 16 + lr) * 200 + ks * 32 + lk * 8];
#pragma unroll
      for (int j = 0; j < 4; ++j)
        acc[j] = __builtin_amdgcn_mfma_f32_16x16x32_bf16(fb[j], fa[ks], acc[j], 0, 0, 0);
    }
#pragma unroll
    for (int j = 0; j < 4; ++j) {
      int n = nt * 64 + j * 16 + lk * 4;
      float v0 = 0.f, v1 = 0.f, v2 = 0.f, v3 = 0.f;
      if (n < 180) {
        f32x4 bv = *(const f32x4*)&pb[n];
        short4v tv = *(const short4v*)(tok + (size_t)row_g * 180 + n);
        v0 = acc[j][0] + bv[0] + rbf(tv[0]);
        v1 = acc[j][1] + bv[1] + rbf(tv[1]);
        v2 = acc[j][2] + bv[2] + rbf(tv[2]);
        v3 = acc[j][3] + bv[3] + rbf(tv[3]);
      }
      *(uint2v*)&T2[row_l * 200 + n] = pack4(v0, v1, v2, v3);
    }
  }
  __syncthreads();

  // ======= LN2: T2 -> H2 (in BsH region) =======
  {
    int rl = w * 16 + (l >> 2), part = l & 3;
    short8 t[6];
    float s = 0.f, s2 = 0.f;
#pragma unroll
    for (int c = 0; c < 6; ++c) {
      t[c] = *(const short8*)&T2[rl * 200 + part * 48 + c * 8];
#pragma unroll
      for (int e = 0; e < 8; ++e) { float v = rbf(t[c][e]); s += v; s2 = fmaf(v, v, s2); }
    }
    s += __shfl_xor(s, 1);  s += __shfl_xor(s, 2);
    s2 += __shfl_xor(s2, 1); s2 += __shfl_xor(s2, 2);
    float mu = s * (1.f / 180.f);
    float rs = rsqrtf(s2 * (1.f / 180.f) - mu * mu + 1e-5f);
    __syncthreads();  // proj Bs no longer needed; safe to overwrite as H2
#pragma unroll
    for (int c = 0; c < 6; ++c) {
#pragma unroll
      for (int e = 0; e < 8; e += 2) {
        int idx = part * 48 + c * 8 + e;
        float h0 = (idx < 180) ? (rbf(t[c][e]) - mu) * rs * g2[idx] + b2[idx] : 0.f;
        float h1 = (idx + 1 < 180) ? (rbf(t[c][e + 1]) - mu) * rs * g2[idx + 1] + b2[idx + 1] : 0.f;
        *(uint32_t*)&BsH[rl * 200 + idx] = pack2(h0, h1);
      }
    }
  }
  __syncthreads();

  // H2 A-frags (K=192)
  short8 fh[6];
  {
#pragma unroll
    for (int ks = 0; ks < 6; ++ks)
      fh[ks] = *(const short8*)&BsH[row_l * 200 + ks * 32 + lk * 8];
  }

  // ======= mlp1 (NT=6, N=360) + gelu -> Mm =======
#pragma unroll
  for (int nt = 0; nt < 6; ++nt) {
    __syncthreads();
    for (int c = tid; c < 1536; c += 256) {
      int n = c / 24, k8 = c % 24;
      *(short8*)&BsH[n * 200 + k8 * 8] =
          *(const short8*)(Bt1 + (size_t)(nt * 64 + n) * 192 + k8 * 8);
    }
    __syncthreads();
    f32x4 acc[4];
#pragma unroll
    for (int j = 0; j < 4; ++j) acc[j] = (f32x4){0.f, 0.f, 0.f, 0.f};
#pragma unroll
    for (int ks = 0; ks < 6; ++ks) {
      short8 fb[4];
#pragma unroll
      for (int j = 0; j < 4; ++j)
        fb[j] = *(const short8*)&BsH[(j * 16 + lr) * 200 + ks * 32 + lk * 8];
#pragma unroll
      for (int j = 0; j < 4; ++j)
        acc[j] = __builtin_amdgcn_mfma_f32_16x16x32_bf16(fb[j], fh[ks], acc[j], 0, 0, 0);
    }
#pragma unroll
    for (int j = 0; j < 4; ++j) {
      int n = nt * 64 + j * 16 + lk * 4;
      float vv[4] = {0.f, 0.f, 0.f, 0.f};
      if (n < 360) {
        f32x4 bv = *(const f32x4*)&b1m[n];
#pragma unroll
        for (int r = 0; r < 4; ++r) {
          float v = acc[j][r] + bv[r];
          float u = 0.7978845608028654f * (v + 0.044715f * v * v * v);
          vv[r] = v / (1.f + __expf(-2.f * u));
        }
      }
      *(uint2v*)&Mm[row_l * 392 + n] = pack4(vv[0], vv[1], vv[2], vv[3]);
    }
  }

  // ======= mlp2 (K=384, NT=3, N=180) + T2 residual -> T2 (tok3, in place) =======
#pragma unroll
  for (int nt = 0; nt < 3; ++nt) {
    __syncthreads();
    for (int c = tid; c < 3072; c += 256) {  // stage B tile 64x384, stride 392
      int n = c / 48, k8 = c % 48;
      *(short8*)&BsH[n * 392 + k8 * 8] =
          *(const short8*)(Bt2 + (size_t)(nt * 64 + n) * 384 + k8 * 8);
    }
    __syncthreads();
    f32x4 acc[4];
#pragma unroll
    for (int j = 0; j < 4; ++j) acc[j] = (f32x4){0.f, 0.f, 0.f, 0.f};
#pragma unroll
    for (int ks = 0; ks < 12; ++ks) {
      short8 fm = *(const short8*)&Mm[row_l * 392 + ks * 32 + lk * 8];
      short8 fb[4];
#pragma unroll
      for (int j = 0; j < 4; ++j)
        fb[j] = *(const short8*)&BsH[(j * 16 + lr) * 392 + ks * 32 + lk * 8];
#pragma unroll
      for (int j = 0; j < 4; ++j)
        acc[j] = __builtin_amdgcn_mfma_f32_16x16x32_bf16(fb[j], fm, acc[j], 0, 0, 0);
    }
#pragma unroll
    for (int j = 0; j < 4; ++j) {
      int n = nt * 64 + j * 16 + lk * 4;
      float v0 = 0.f, v1 = 0.f, v2 = 0.f, v3 = 0.f;
      if (n < 180) {
        f32x4 bv = *(const f32x4*)&b2m[n];
        v0 = acc[j][0] + bv[0] + rbf(T2[row_l * 200 + n]);
        v1 = acc[j][1] + bv[1] + rbf(T2[row_l * 200 + n + 1]);
        v2 = acc[j][2] + bv[2] + rbf(T2[row_l * 200 + n + 2]);
        v3 = acc[j][3] + bv[3] + rbf(T2[row_l * 200 + n + 3]);
      }
      *(uint2v*)&T2[row_l * 200 + n] = pack4(v0, v1, v2, v3);
    }
  }

  // ======= up (N=48) from T2 (tok3) =======
  {
    __syncthreads();
    for (int c = tid; c < 1536; c += 256) {
      int n = c / 24, k8 = c % 24;
      *(short8*)&BsH[n * 200 + k8 * 8] = *(const short8*)(Btu + (size_t)n * 192 + k8 * 8);
    }
    __syncthreads();
    short8 ft[6];
#pragma unroll
    for (int ks = 0; ks < 6; ++ks)
      ft[ks] = *(const short8*)&T2[row_l * 200 + ks * 32 + lk * 8];
    f32x4 acc[3];
#pragma unroll
    for (int j = 0; j < 3; ++j) acc[j] = (f32x4){0.f, 0.f, 0.f, 0.f};
#pragma unroll
    for (int ks = 0; ks < 6; ++ks) {
      short8 fb[3];
#pragma unroll
      for (int j = 0; j < 3; ++j)
        fb[j] = *(const short8*)&BsH[(j * 16 + lr) * 200 + ks * 32 + lk * 8];
#pragma unroll
      for (int j = 0; j < 3; ++j)
        acc[j] = __builtin_amdgcn_mfma_f32_16x16x32_bf16(fb[j], ft[ks], acc[j], 0, 0, 0);
    }
#pragma unroll
    for (int j = 0; j < 3; ++j) {
      int n = j * 16 + lk * 4;
      if (n < 48) {
        f32x4 bv = *(const f32x4*)&bu[n];
        *(uint2v*)(up + (size_t)row_g * 48 + n) =
            pack4(acc[j][0] + bv[0], acc[j][1] + bv[1], acc[j][2] + bv[2], acc[j][3] + bv[3]);
      }
    }
  }
}

// ---------------- bicubic weights (jax Keys a=-0.5, half-pixel, edge renorm) ----------------
__device__ const float c_cubw[4][4] = {
    {-0.0439453125f, 0.3896484375f, 0.7275390625f, -0.0732421875f},
    {-0.0068359375f, 0.0908203125f, 0.9638671875f, -0.0478515625f},
    {-0.0478515625f, 0.9638671875f, 0.0908203125f, -0.0068359375f},
    {-0.0732421875f, 0.7275390625f, 0.3896484375f, -0.0439453125f},
};

__device__ __forceinline__ void cubw(int r, int ph, float* w, int& base) {
  base = r + ((ph < 2) ? -2 : -1);
  float sum = 0.f;
#pragma unroll
  for (int i = 0; i < 4; ++i) {
    int idx = base + i;
    float wi = (idx >= 0 && idx < 64) ? c_cubw[ph][i] : 0.f;
    w[i] = wi; sum += wi;
  }
  float inv = 1.f / sum;
#pragma unroll
  for (int i = 0; i < 4; ++i) w[i] *= inv;
}

// ---------------- blend: pixel-shuffle of up + bicubic + mask blend ----------------
__global__ __launch_bounds__(256) void k_blend(
    const bf16* __restrict__ up, const float* __restrict__ x,
    const float* __restrict__ maskp, float* __restrict__ sr) {
  int idx = blockIdx.x * 256 + threadIdx.x;
  int ch = idx >> 20;
  int rem = idx & 1048575;
  int gR = rem >> 10, gC = rem & 1023;
  int th = gR >> 8, tw = gC >> 8;
  int t = th * 4 + tw;
  int R = gR & 255, C = gC & 255;
  int r = R >> 2, a = R & 3, c = C >> 2, b = C & 3;
  float m = maskp[t];
  float outv;
  if (m > 0.5f) {
    int wi = r >> 4, u = r & 15, wj = c >> 4, v = c & 15;
    int wrow = (t * 16 + wi * 4 + wj) * 256 + u * 16 + v;
    outv = bf2f(up[(size_t)wrow * 48 + a * 12 + b * 3 + ch]);
  } else {
    float wy[4], wx[4];
    int yb, xb;
    cubw(r, a, wy, yb);
    cubw(c, b, wx, xb);
    const float* xc = x + ch * 65536;
    float neg = 0.f;
#pragma unroll
    for (int i = 0; i < 4; ++i) {
      int yi = yb + i;
      if (yi < 0 || yi > 63) continue;
      float rowsum = 0.f;
#pragma unroll
      for (int j = 0; j < 4; ++j) {
        int xj = xb + j;
        if (xj < 0 || xj > 63) continue;
        rowsum = fmaf(wx[j], xc[(th * 64 + yi) * 256 + tw * 64 + xj], rowsum);
      }
      neg = fmaf(wy[i], rowsum, neg);
    }
    outv = neg;
  }
  sr[idx] = outv;
}

// ---------------- launcher ----------------
extern "C" void kernel_launch(void* const* d_in, const int* in_sizes, int n_in,
                              void* d_out, int out_size, void* d_ws, size_t ws_size,
                              hipStream_t stream) {
  const float* x     = (const float*)d_in[0];
  const float* gu    = (const float*)d_in[1];
  const float* s1w   = (const float*)d_in[2];
  const float* s1b   = (const float*)d_in[3];
  const float* s2w   = (const float*)d_in[4];
  const float* s2b   = (const float*)d_in[5];
  const float* s3w   = (const float*)d_in[6];
  const float* s3b   = (const float*)d_in[7];
  const float* ew    = (const float*)d_in[8];
  const float* ebias = (const float*)d_in[9];
  const float* ln1g  = (const float*)d_in[10];
  const float* ln1b  = (const float*)d_in[11];
  const float* qkvw  = (const float*)d_in[12];
  const float* qkvb  = (const float*)d_in[13];
  const float* projw = (const float*)d_in[14];
  const float* projb = (const float*)d_in[15];
  const float* ln2g  = (const float*)d_in[16];
  const float* ln2b  = (const float*)d_in[17];
  const float* mlp1w = (const float*)d_in[18];
  const float* mlp1b = (const float*)d_in[19];
  const float* mlp2w = (const float*)d_in[20];
  const float* mlp2b = (const float*)d_in[21];
  const float* upw   = (const float*)d_in[22];
  const float* upb   = (const float*)d_in[23];

  float* out = (float*)d_out;
  float* sr  = out;                 // 3*1024*1024
  float* f3o = out + 3145728;       // 16*2
  float* f2o = f3o + 32;            // 16*32
  float* f1o = f2o + 512;           // 16*64

  char* ws = (char*)d_ws;
  bf16* tok  = (bf16*)(ws);                   // 65536*180 = 23,592,960 B
  bf16* ABuf = (bf16*)(ws + 23592960);        // 65536*192 = 25,165,824 B (LN1 out, then av)
  bf16* Qp   = (bf16*)(ws + 48758784);        // 65536*192
  bf16* Kp   = (bf16*)(ws + 73924608);        // 65536*192
  bf16* Vp   = (bf16*)(ws + 99090432);        // 65536*192
  float* maskp   = (float*)(ws + 124256256);  // 64 B
  bf16* Bt_qkv  = (bf16*)(ws + 124256320);    // 576*192*2 = 221,184
  bf16* Bt_proj = (bf16*)(ws + 124477504);    // 192*192*2 = 73,728
  bf16* Bt_mlp1 = (bf16*)(ws + 124551232);    // 384*192*2 = 147,456
  bf16* Bt_mlp2 = (bf16*)(ws + 124698688);    // 192*384*2 = 147,456
  bf16* Bt_up   = (bf16*)(ws + 124846144);    // 64*192*2  = 24,576
  float* biasq  = (float*)(ws + 124870720);   // 576*4 = 2,304
  bf16* up      = (bf16*)(ws + 124873088);    // 65536*48*2 = 6,291,456
  bf16* av = ABuf;  // alias: ABuf dead after k_qkv

  k_selector<<<16, 64, 0, stream>>>(x, gu, s1w, s1b, s2w, s2b, s3w, s3b, f1o, f2o, f3o, maskp);
  k_packB<<<1203, 256, 0, stream>>>(qkvw, projw, mlp1w, mlp2w, upw, qkvb,
                                    Bt_qkv, Bt_proj, Bt_mlp1, Bt_mlp2, Bt_up, biasq);
  k_embed<<<16384, 256, 0, stream>>>(x, ew, ebias, ln1g, ln1b, tok, ABuf);
  k_qkv<<<1024, 256, 0, stream>>>(ABuf, Bt_qkv, biasq, Qp, Kp, Vp);
  k_attn2<<<1536, 256, 0, stream>>>(Qp, Kp, Vp, av);
  k_post<<<1024, 256, 0, stream>>>(av, tok, Bt_proj, projb, ln2g, ln2b,
                                   Bt_mlp1, mlp1b, Bt_mlp2, mlp2b, Bt_up, upb, up);
  k_blend<<<12288, 256, 0, stream>>>(up, x, maskp, sr);
}

// Round 8
// 295.894 us; speedup vs baseline: 1.4954x; 1.2377x over previous
//
#include <hip/hip_runtime.h>
#include <hip/hip_bf16.h>
#include <cstdint>

typedef __hip_bfloat16 bf16;
typedef __attribute__((ext_vector_type(8))) short short8;
typedef __attribute__((ext_vector_type(4))) short short4v;
typedef __attribute__((ext_vector_type(4))) float f32x4;
typedef __attribute__((ext_vector_type(2))) unsigned int uint2v;

__device__ __forceinline__ float bf2f(bf16 v) { return __bfloat162float(v); }
__device__ __forceinline__ bf16  f2bf(float v) { return __float2bfloat16(v); }
__device__ __forceinline__ float rbf(short s) {
  union { uint32_t u; float f; } c; c.u = ((uint32_t)(uint16_t)s) << 16; return c.f;
}
__device__ __forceinline__ uint32_t pack2(float a, float b) {
  bf16 x = f2bf(a), y = f2bf(b);
  return (uint32_t)(*(uint16_t*)&x) | ((uint32_t)(*(uint16_t*)&y) << 16);
}
__device__ __forceinline__ uint2v pack4(float a, float b, float c, float d) {
  uint2v r; r[0] = pack2(a, b); r[1] = pack2(c, d); return r;
}
// granule swizzle: XOR low-3 bits of 8-elem granule index with row&7
__device__ __forceinline__ int swz(int row, int g) { return g ^ (row & 7); }

// window-order row m -> token index (t*4096 + p)
__device__ __forceinline__ int win_to_token(int m) {
  int n = m >> 8, l = m & 255;
  int t = n >> 4, win = n & 15;
  int wi = win >> 2, wj = win & 3;
  int u = l >> 4, v = l & 15;
  return (t << 12) | ((wi * 16 + u) << 6) | (wj * 16 + v);
}

// ---------------- merged: weight packing + selector MLP ----------------
__global__ __launch_bounds__(256) void k_packsel(
    const float* __restrict__ qkvw, const float* __restrict__ projw,
    const float* __restrict__ mlp1w, const float* __restrict__ mlp2w,
    const float* __restrict__ upw, const float* __restrict__ qkvb,
    bf16* __restrict__ Bt_qkv, bf16* __restrict__ Bt_proj,
    bf16* __restrict__ Bt_mlp1, bf16* __restrict__ Bt_mlp2,
    bf16* __restrict__ Bt_up, float* __restrict__ biasq,
    const float* __restrict__ x, const float* __restrict__ gu,
    const float* __restrict__ s1w, const float* __restrict__ s1b,
    const float* __restrict__ s2w, const float* __restrict__ s2b,
    const float* __restrict__ s3w, const float* __restrict__ s3b,
    float* __restrict__ f1o, float* __restrict__ f2o, float* __restrict__ f3o,
    float* __restrict__ maskp) {
  if (blockIdx.x < 1203) {
    int idx = blockIdx.x * 256 + threadIdx.x;
    const int e0 = 576 * 192, e1 = e0 + 192 * 192, e2 = e1 + 384 * 192,
              e3 = e2 + 192 * 384, e4 = e3 + 64 * 192, e5 = e4 + 576;
    if (idx < e0) {
      int np = idx / 192, k = idx % 192;
      int buf = np / 192, colp = np % 192;
      int hd = colp >> 5, dd = colp & 31;
      float v = 0.f;
      if (dd < 30 && k < 180) v = qkvw[(size_t)k * 540 + buf * 180 + hd * 30 + dd];
      Bt_qkv[idx] = f2bf(v);
    } else if (idx < e1) {
      int off = idx - e0; int n = off / 192, kp = off % 192;
      int hd = kp >> 5, dd = kp & 31;
      float v = (dd < 30 && n < 180) ? projw[(size_t)(hd * 30 + dd) * 180 + n] : 0.f;
      Bt_proj[off] = f2bf(v);
    } else if (idx < e2) {
      int off = idx - e1; int n = off / 192, k = off % 192;
      Bt_mlp1[off] = f2bf((k < 180 && n < 360) ? mlp1w[(size_t)k * 360 + n] : 0.f);
    } else if (idx < e3) {
      int off = idx - e2; int n = off / 384, k = off % 384;
      Bt_mlp2[off] = f2bf((k < 360 && n < 180) ? mlp2w[(size_t)k * 180 + n] : 0.f);
    } else if (idx < e4) {
      int off = idx - e3; int n = off / 192, k = off % 192;
      Bt_up[off] = f2bf((k < 180 && n < 48) ? upw[(size_t)k * 48 + n] : 0.f);
    } else if (idx < e5) {
      int np = idx - e4;
      int buf = np / 192, colp = np % 192;
      int hd = colp >> 5, dd = colp & 31;
      biasq[np] = (dd < 30) ? qkvb[buf * 180 + hd * 30 + dd] : 0.f;
    }
    return;
  }
  // ---- selector (blocks 1203..1218), 256 threads ----
  int t = blockIdx.x - 1203;
  int tid = threadIdx.x;
  int th = t >> 2, tw = t & 3;
  __shared__ float pooled[192];
  __shared__ float red[256];
  __shared__ float f1s[64], f2s[32], f3s[2];
  if (tid < 192) {
    int ch = tid % 3, j = (tid / 3) & 7, i = tid / 24;
    const float* xp = x + ch * 65536 + (th * 64 + i * 8) * 256 + (tw * 64 + j * 8);
    float s = 0.f;
#pragma unroll
    for (int a = 0; a < 8; ++a)
#pragma unroll
      for (int b = 0; b < 8; ++b) s += xp[a * 256 + b];
    pooled[tid] = s * (1.0f / 64.0f);
  }
  __syncthreads();
  {  // fc1: 64 outs, 4 k-parts of 48
    int o = tid & 63, part = tid >> 6;
    float s = 0.f;
    for (int k = part * 48; k < part * 48 + 48; ++k) s = fmaf(pooled[k], s1w[k * 64 + o], s);
    red[tid] = s;
  }
  __syncthreads();
  if (tid < 64) {
    float v = red[tid] + red[tid + 64] + red[tid + 128] + red[tid + 192] + s1b[tid];
    f1o[t * 64 + tid] = v;
    f1s[tid] = fmaxf(v, 0.f);
  }
  __syncthreads();
  {  // fc2: 32 outs, 8 k-parts of 8
    int o = tid & 31, part = tid >> 5;
    float s = 0.f;
    for (int k = part * 8; k < part * 8 + 8; ++k) s = fmaf(f1s[k], s2w[k * 32 + o], s);
    red[tid] = s;
  }
  __syncthreads();
  if (tid < 32) {
    float v = s2b[tid];
#pragma unroll
    for (int p = 0; p < 8; ++p) v += red[tid + p * 32];
    f2o[t * 32 + tid] = v;
    f2s[tid] = fmaxf(v, 0.f);
  }
  __syncthreads();
  if (tid < 2) {
    float s = s3b[tid];
    for (int k = 0; k < 32; ++k) s = fmaf(f2s[k], s3w[k * 2 + tid], s);
    f3o[t * 2 + tid] = s;
    f3s[tid] = s;
  }
  __syncthreads();
  if (tid == 0) {
    float g0 = -logf(-logf(gu[t * 2 + 0] + 1e-10f) + 1e-10f);
    float g1 = -logf(-logf(gu[t * 2 + 1] + 1e-10f) + 1e-10f);
    maskp[t] = (f3s[1] + g1 > f3s[0] + g0) ? 1.0f : 0.0f;
  }
}

// ---------------- embed (3->180) + LN1 applied, outputs window-major ----------------
__global__ __launch_bounds__(256) void k_embed(
    const float* __restrict__ x, const float* __restrict__ ew,
    const float* __restrict__ eb, const float* __restrict__ g1,
    const float* __restrict__ b1, bf16* __restrict__ tok,
    bf16* __restrict__ Aq) {
  int wrow = blockIdx.x * 4 + (threadIdx.x >> 6);
  int lane = threadIdx.x & 63;
  int token = win_to_token(wrow);
  int t = token >> 12, p = token & 4095;
  int r = p >> 6, c = p & 63;
  int gh = (t >> 2) * 64 + r, gw = (t & 3) * 64 + c;
  float x0 = x[gh * 256 + gw];
  float x1 = x[65536 + gh * 256 + gw];
  float x2 = x[131072 + gh * 256 + gw];
  float v[3];
  float s = 0.f, s2 = 0.f;
#pragma unroll
  for (int i = 0; i < 3; ++i) {
    int e = lane + i * 64;
    float vv = 0.f;
    if (e < 180) {
      vv = eb[e];
      vv = fmaf(x0, ew[e], vv);
      vv = fmaf(x1, ew[180 + e], vv);
      vv = fmaf(x2, ew[360 + e], vv);
      tok[(size_t)wrow * 180 + e] = f2bf(vv);
      s += vv; s2 = fmaf(vv, vv, s2);
    }
    v[i] = vv;
  }
#pragma unroll
  for (int off = 32; off; off >>= 1) { s += __shfl_xor(s, off); s2 += __shfl_xor(s2, off); }
  float mu = s * (1.f / 180.f);
  float rs = rsqrtf(s2 * (1.f / 180.f) - mu * mu + 1e-5f);
#pragma unroll
  for (int i = 0; i < 3; ++i) {
    int e = lane + i * 64;
    if (e < 192) {
      float a = (e < 180) ? ((v[i] - mu) * rs * g1[e] + b1[e]) : 0.f;
      Aq[(size_t)wrow * 192 + e] = f2bf(a);
    }
  }
}

// ---------------- qkv GEMM: swapped operands, 8B coalesced row stores ----------------
__global__ __launch_bounds__(256) void k_qkv(
    const bf16* __restrict__ A, const bf16* __restrict__ Bt,
    const float* __restrict__ biasq, bf16* __restrict__ Qp,
    bf16* __restrict__ Kp, bf16* __restrict__ Vp) {
  const int tid = threadIdx.x;
  const int w = tid >> 6, l = tid & 63;
  const int lr = l & 15, lk = l >> 4;
  const int row_g = blockIdx.x * 64 + w * 16 + lr;
  short8 fa[6];
  const bf16* Ab = A + (size_t)row_g * 192 + lk * 8;
#pragma unroll
  for (int ks = 0; ks < 6; ++ks) fa[ks] = *(const short8*)(Ab + ks * 32);
#pragma unroll
  for (int nt = 0; nt < 9; ++nt) {
    const bf16* Bb = Bt + (size_t)nt * 64 * 192;
    f32x4 acc[4];
#pragma unroll
    for (int j = 0; j < 4; ++j) acc[j] = (f32x4){0.f, 0.f, 0.f, 0.f};
#pragma unroll
    for (int ks = 0; ks < 6; ++ks) {
      short8 fb[4];
#pragma unroll
      for (int j = 0; j < 4; ++j)
        fb[j] = *(const short8*)(Bb + (size_t)(j * 16 + lr) * 192 + ks * 32 + lk * 8);
#pragma unroll
      for (int j = 0; j < 4; ++j)
        acc[j] = __builtin_amdgcn_mfma_f32_16x16x32_bf16(fb[j], fa[ks], acc[j], 0, 0, 0);
    }
    bf16* dst = (nt < 3) ? Qp : (nt < 6) ? Kp : Vp;
    int c0 = (nt % 3) * 64;
#pragma unroll
    for (int j = 0; j < 4; ++j) {
      int np = nt * 64 + j * 16 + lk * 4;
      f32x4 bv = *(const f32x4*)&biasq[np];
      *(uint2v*)(dst + (size_t)row_g * 192 + c0 + j * 16 + lk * 4) =
          pack4(acc[j][0] + bv[0], acc[j][1] + bv[1], acc[j][2] + bv[2], acc[j][3] + bv[3]);
    }
  }
}

// ---------------- MFMA attention: block = (window, head), swapped PV ----------------
__global__ __launch_bounds__(256) void k_attn2(
    const bf16* __restrict__ Qp, const bf16* __restrict__ Kp,
    const bf16* __restrict__ Vp, bf16* __restrict__ av) {
  const int blk = blockIdx.x;
  const int win = blk / 6, hd = blk % 6;
  const int tid = threadIdx.x;
  const int w = tid >> 6, l = tid & 63;
  const int lr = l & 15, lk = l >> 4;
  const float scale = 0.18257418583505536f;  // 1/sqrt(30)

  __shared__ bf16 Ks[256][40];
  __shared__ bf16 Vs[32][264];
  __shared__ bf16 Ps[4][16][264];

  {  // stage K rows
    const bf16* src = Kp + (size_t)(win * 256 + tid) * 192 + hd * 32;
#pragma unroll
    for (int c = 0; c < 4; ++c)
      *(short8*)&Ks[tid][c * 8] = *(const short8*)(src + c * 8);
  }
  {  // stage V rows -> transposed Vs[d][key]
    const bf16* src = Vp + (size_t)(win * 256 + tid) * 192 + hd * 32;
    short8 vv[4];
#pragma unroll
    for (int c = 0; c < 4; ++c) vv[c] = *(const short8*)(src + c * 8);
#pragma unroll
    for (int c = 0; c < 4; ++c)
#pragma unroll
      for (int e = 0; e < 8; ++e)
        *(short*)&Vs[c * 8 + e][tid] = vv[c][e];
  }
  __syncthreads();

  for (int qt = 0; qt < 4; ++qt) {
    const int qbase = qt * 64 + w * 16;
    short8 fq = *(const short8*)(Qp + (size_t)(win * 256 + qbase + lr) * 192 + hd * 32 + lk * 8);
    f32x4 accS[16];
#pragma unroll
    for (int kt = 0; kt < 16; ++kt) {
      short8 fk = *(const short8*)(&Ks[kt * 16 + lr][lk * 8]);
      accS[kt] = __builtin_amdgcn_mfma_f32_16x16x32_bf16(
          fk, fq, (f32x4){0.f, 0.f, 0.f, 0.f}, 0, 0, 0);
    }
    float mraw = -1e30f;
#pragma unroll
    for (int kt = 0; kt < 16; ++kt)
#pragma unroll
      for (int r = 0; r < 4; ++r) mraw = fmaxf(mraw, accS[kt][r]);
    mraw = fmaxf(mraw, __shfl_xor(mraw, 16));
    mraw = fmaxf(mraw, __shfl_xor(mraw, 32));
    const float mc = mraw * scale;
    float lsum = 0.f;
#pragma unroll
    for (int kt = 0; kt < 16; ++kt) {
      float p0 = __expf(fmaf(accS[kt][0], scale, -mc));
      float p1 = __expf(fmaf(accS[kt][1], scale, -mc));
      float p2 = __expf(fmaf(accS[kt][2], scale, -mc));
      float p3 = __expf(fmaf(accS[kt][3], scale, -mc));
      lsum += (p0 + p1) + (p2 + p3);
      *(uint32_t*)&Ps[w][lr][kt * 16 + lk * 4]     = pack2(p0, p1);
      *(uint32_t*)&Ps[w][lr][kt * 16 + lk * 4 + 2] = pack2(p2, p3);
    }
    lsum += __shfl_xor(lsum, 16);
    lsum += __shfl_xor(lsum, 32);
    __syncthreads();
    f32x4 accO0 = (f32x4){0.f, 0.f, 0.f, 0.f};
    f32x4 accO1 = (f32x4){0.f, 0.f, 0.f, 0.f};
#pragma unroll
    for (int ks = 0; ks < 8; ++ks) {
      short8 fp  = *(const short8*)(&Ps[w][lr][ks * 32 + lk * 8]);
      short8 fv0 = *(const short8*)(&Vs[lr][ks * 32 + lk * 8]);
      short8 fv1 = *(const short8*)(&Vs[16 + lr][ks * 32 + lk * 8]);
      accO0 = __builtin_amdgcn_mfma_f32_16x16x32_bf16(fv0, fp, accO0, 0, 0, 0);
      accO1 = __builtin_amdgcn_mfma_f32_16x16x32_bf16(fv1, fp, accO1, 0, 0, 0);
    }
    float invl = 1.f / lsum;
    bf16* avrow = av + (size_t)(win * 256 + qbase + lr) * 192 + hd * 32;
    *(uint2v*)(avrow + lk * 4) =
        pack4(accO0[0] * invl, accO0[1] * invl, accO0[2] * invl, accO0[3] * invl);
    *(uint2v*)(avrow + 16 + lk * 4) =
        pack4(accO1[0] * invl, accO1[1] * invl, accO1[2] * invl, accO1[3] * invl);
    __syncthreads();
  }
}

// ---------------- fused post-attn: proj+res -> LN2 -> mlp1(gelu)⊕mlp2+res -> up ----
// 64 rows/block, 4 waves. LDS 72KB -> 2 blocks/CU. tok2 in f32 regs. XOR-swizzled LDS.
__global__ __launch_bounds__(256) void k_post(
    const bf16* __restrict__ av, const bf16* __restrict__ tok,
    const bf16* __restrict__ Btp, const float* __restrict__ pb,
    const float* __restrict__ g2, const float* __restrict__ b2,
    const bf16* __restrict__ Bt1, const float* __restrict__ b1m,
    const bf16* __restrict__ Bt2, const float* __restrict__ b2m,
    const bf16* __restrict__ Btu, const float* __restrict__ bu,
    bf16* __restrict__ up) {
  __shared__ bf16 Bs[64 * 192];  // B tile [n64][k192] swizzled; or mlp2 slab [192][64]
  __shared__ bf16 T2[64 * 192];  // tok3 (for up's A-frags)
  __shared__ bf16 Hm[64 * 192];  // H2 (LN2 out), then per-nt mid slab (granules 0..7)
  const int tid = threadIdx.x;
  const int w = tid >> 6, l = tid & 63;
  const int lr = l & 15, lk = l >> 4;
  const int row_l = w * 16 + lr;
  const int row_g = blockIdx.x * 64 + row_l;
  const int half = (lk & 1) * 4;

  // av A-frags
  short8 fa[6];
  {
    const bf16* ab = av + (size_t)row_g * 192 + lk * 8;
#pragma unroll
    for (int ks = 0; ks < 6; ++ks) fa[ks] = *(const short8*)(ab + ks * 32);
  }

  // ======= proj + bias + tok residual -> t2 regs =======
  f32x4 t2v[3][4];
#pragma unroll
  for (int nt = 0; nt < 3; ++nt) {
    __syncthreads();
    for (int c = tid; c < 1536; c += 256) {
      int n = c / 24, g = c % 24;
      *(short8*)&Bs[n * 192 + swz(n, g) * 8] =
          *(const short8*)(Btp + (size_t)(nt * 64 + n) * 192 + g * 8);
    }
    __syncthreads();
    f32x4 acc[4];
#pragma unroll
    for (int j = 0; j < 4; ++j) acc[j] = (f32x4){0.f, 0.f, 0.f, 0.f};
#pragma unroll
    for (int ks = 0; ks < 6; ++ks) {
      short8 fb[4];
#pragma unroll
      for (int j = 0; j < 4; ++j) {
        int rn = j * 16 + lr;
        fb[j] = *(const short8*)&Bs[rn * 192 + swz(rn, ks * 4 + lk) * 8];
      }
#pragma unroll
      for (int j = 0; j < 4; ++j)
        acc[j] = __builtin_amdgcn_mfma_f32_16x16x32_bf16(fb[j], fa[ks], acc[j], 0, 0, 0);
    }
#pragma unroll
    for (int j = 0; j < 4; ++j) {
      int n = nt * 64 + j * 16 + lk * 4;
      if (n < 180) {
        f32x4 bv = *(const f32x4*)&pb[n];
        short4v tv = *(const short4v*)(tok + (size_t)row_g * 180 + n);
#pragma unroll
        for (int q = 0; q < 4; ++q) t2v[nt][j][q] = acc[j][q] + bv[q] + rbf(tv[q]);
      } else {
        t2v[nt][j] = (f32x4){0.f, 0.f, 0.f, 0.f};
      }
    }
  }

  // ======= LN2 stats from regs, H2 -> Hm =======
  {
    float s = 0.f, s2 = 0.f;
#pragma unroll
    for (int nt = 0; nt < 3; ++nt)
#pragma unroll
      for (int j = 0; j < 4; ++j)
#pragma unroll
        for (int q = 0; q < 4; ++q) { float v = t2v[nt][j][q]; s += v; s2 = fmaf(v, v, s2); }
    s += __shfl_xor(s, 16);  s += __shfl_xor(s, 32);
    s2 += __shfl_xor(s2, 16); s2 += __shfl_xor(s2, 32);
    float mu = s * (1.f / 180.f);
    float rs = rsqrtf(s2 * (1.f / 180.f) - mu * mu + 1e-5f);
#pragma unroll
    for (int nt = 0; nt < 3; ++nt)
#pragma unroll
      for (int j = 0; j < 4; ++j) {
        int n = nt * 64 + j * 16 + lk * 4;
        float h[4] = {0.f, 0.f, 0.f, 0.f};
        if (n < 180) {
          f32x4 gv = *(const f32x4*)&g2[n];
          f32x4 bv = *(const f32x4*)&b2[n];
#pragma unroll
          for (int q = 0; q < 4; ++q) h[q] = (t2v[nt][j][q] - mu) * rs * gv[q] + bv[q];
        }
        int g = nt * 8 + j * 2 + (lk >> 1);
        *(uint2v*)&Hm[row_l * 192 + swz(row_l, g) * 8 + half] = pack4(h[0], h[1], h[2], h[3]);
      }
  }
  __syncthreads();
  short8 fh[6];
#pragma unroll
  for (int ks = 0; ks < 6; ++ks)
    fh[ks] = *(const short8*)&Hm[row_l * 192 + swz(row_l, ks * 4 + lk) * 8];

  // ======= mlp1(gelu) fused with mlp2 accumulation =======
  f32x4 acc2[3][4];
#pragma unroll
  for (int t = 0; t < 3; ++t)
#pragma unroll
    for (int j = 0; j < 4; ++j) acc2[t][j] = (f32x4){0.f, 0.f, 0.f, 0.f};
#pragma unroll
  for (int nt = 0; nt < 6; ++nt) {
    __syncthreads();  // prev fm reads / fh reads done
    for (int c = tid; c < 1536; c += 256) {
      int n = c / 24, g = c % 24;
      *(short8*)&Bs[n * 192 + swz(n, g) * 8] =
          *(const short8*)(Bt1 + (size_t)(nt * 64 + n) * 192 + g * 8);
    }
    __syncthreads();
    f32x4 acc1[4];
#pragma unroll
    for (int j = 0; j < 4; ++j) acc1[j] = (f32x4){0.f, 0.f, 0.f, 0.f};
#pragma unroll
    for (int ks = 0; ks < 6; ++ks) {
      short8 fb[4];
#pragma unroll
      for (int j = 0; j < 4; ++j) {
        int rn = j * 16 + lr;
        fb[j] = *(const short8*)&Bs[rn * 192 + swz(rn, ks * 4 + lk) * 8];
      }
#pragma unroll
      for (int j = 0; j < 4; ++j)
        acc1[j] = __builtin_amdgcn_mfma_f32_16x16x32_bf16(fb[j], fh[ks], acc1[j], 0, 0, 0);
    }
    // gelu + bias -> mid slab (Hm granules 0..7)
#pragma unroll
    for (int j = 0; j < 4; ++j) {
      int n = nt * 64 + j * 16 + lk * 4;
      float m4[4] = {0.f, 0.f, 0.f, 0.f};
      if (n < 360) {
        f32x4 bv = *(const f32x4*)&b1m[n];
#pragma unroll
        for (int q = 0; q < 4; ++q) {
          float v = acc1[j][q] + bv[q];
          float u = 0.7978845608028654f * (v + 0.044715f * v * v * v);
          m4[q] = v / (1.f + __expf(-2.f * u));
        }
      }
      int g = j * 2 + (lk >> 1);
      *(uint2v*)&Hm[row_l * 192 + swz(row_l, g) * 8 + half] = pack4(m4[0], m4[1], m4[2], m4[3]);
    }
    __syncthreads();  // mid slab visible; Bs(B1) reads done
    // stage mlp2 k-slab: [192 n][64 k] swizzled
    for (int c = tid; c < 1536; c += 256) {
      int n = c / 8, g = c % 8;
      *(short8*)&Bs[n * 64 + swz(n, g) * 8] =
          *(const short8*)(Bt2 + (size_t)n * 384 + nt * 64 + g * 8);
    }
    __syncthreads();
    short8 fm[2];
#pragma unroll
    for (int s = 0; s < 2; ++s)
      fm[s] = *(const short8*)&Hm[row_l * 192 + swz(row_l, s * 4 + lk) * 8];
#pragma unroll
    for (int s = 0; s < 2; ++s)
#pragma unroll
      for (int t = 0; t < 3; ++t)
#pragma unroll
        for (int j = 0; j < 4; ++j) {
          int rn = t * 64 + j * 16 + lr;
          short8 fb2 = *(const short8*)&Bs[rn * 64 + swz(rn, s * 4 + lk) * 8];
          acc2[t][j] = __builtin_amdgcn_mfma_f32_16x16x32_bf16(fb2, fm[s], acc2[t][j], 0, 0, 0);
        }
  }

  // ======= tok3 = mlp2 + bias + t2(regs) -> T2 LDS =======
#pragma unroll
  for (int t = 0; t < 3; ++t)
#pragma unroll
    for (int j = 0; j < 4; ++j) {
      int n = t * 64 + j * 16 + lk * 4;
      float o4[4] = {0.f, 0.f, 0.f, 0.f};
      if (n < 180) {
        f32x4 bv = *(const f32x4*)&b2m[n];
#pragma unroll
        for (int q = 0; q < 4; ++q) o4[q] = acc2[t][j][q] + bv[q] + t2v[t][j][q];
      }
      int g = t * 8 + j * 2 + (lk >> 1);
      *(uint2v*)&T2[row_l * 192 + swz(row_l, g) * 8 + half] = pack4(o4[0], o4[1], o4[2], o4[3]);
    }
  __syncthreads();  // T2 visible; Bs(mlp2 slab) reads done

  // ======= up (N=48) =======
  for (int c = tid; c < 1536; c += 256) {
    int n = c / 24, g = c % 24;
    *(short8*)&Bs[n * 192 + swz(n, g) * 8] =
        *(const short8*)(Btu + (size_t)n * 192 + g * 8);
  }
  __syncthreads();
  short8 ft[6];
#pragma unroll
  for (int ks = 0; ks < 6; ++ks)
    ft[ks] = *(const short8*)&T2[row_l * 192 + swz(row_l, ks * 4 + lk) * 8];
  f32x4 acc3[3];
#pragma unroll
  for (int j = 0; j < 3; ++j) acc3[j] = (f32x4){0.f, 0.f, 0.f, 0.f};
#pragma unroll
  for (int ks = 0; ks < 6; ++ks) {
    short8 fb[3];
#pragma unroll
    for (int j = 0; j < 3; ++j) {
      int rn = j * 16 + lr;
      fb[j] = *(const short8*)&Bs[rn * 192 + swz(rn, ks * 4 + lk) * 8];
    }
#pragma unroll
    for (int j = 0; j < 3; ++j)
      acc3[j] = __builtin_amdgcn_mfma_f32_16x16x32_bf16(fb[j], ft[ks], acc3[j], 0, 0, 0);
  }
#pragma unroll
  for (int j = 0; j < 3; ++j) {
    int n = j * 16 + lk * 4;
    f32x4 bv = *(const f32x4*)&bu[n];
    *(uint2v*)(up + (size_t)row_g * 48 + n) =
        pack4(acc3[j][0] + bv[0], acc3[j][1] + bv[1], acc3[j][2] + bv[2], acc3[j][3] + bv[3]);
  }
}

// ---------------- bicubic weights (jax Keys a=-0.5, half-pixel, edge renorm) ----------------
__device__ const float c_cubw[4][4] = {
    {-0.0439453125f, 0.3896484375f, 0.7275390625f, -0.0732421875f},
    {-0.0068359375f, 0.0908203125f, 0.9638671875f, -0.0478515625f},
    {-0.0478515625f, 0.9638671875f, 0.0908203125f, -0.0068359375f},
    {-0.0732421875f, 0.7275390625f, 0.3896484375f, -0.0439453125f},
};

__device__ __forceinline__ void cubw(int r, int ph, float* w, int& base) {
  base = r + ((ph < 2) ? -2 : -1);
  float sum = 0.f;
#pragma unroll
  for (int i = 0; i < 4; ++i) {
    int idx = base + i;
    float wi = (idx >= 0 && idx < 64) ? c_cubw[ph][i] : 0.f;
    w[i] = wi; sum += wi;
  }
  float inv = 1.f / sum;
#pragma unroll
  for (int i = 0; i < 4; ++i) w[i] *= inv;
}

// ---------------- blend: pixel-shuffle of up + bicubic + mask blend ----------------
__global__ __launch_bounds__(256) void k_blend(
    const bf16* __restrict__ up, const float* __restrict__ x,
    const float* __restrict__ maskp, float* __restrict__ sr) {
  int idx = blockIdx.x * 256 + threadIdx.x;
  int ch = idx >> 20;
  int rem = idx & 1048575;
  int gR = rem >> 10, gC = rem & 1023;
  int th = gR >> 8, tw = gC >> 8;
  int t = th * 4 + tw;
  int R = gR & 255, C = gC & 255;
  int r = R >> 2, a = R & 3, c = C >> 2, b = C & 3;
  float m = maskp[t];
  float outv;
  if (m > 0.5f) {
    int wi = r >> 4, u = r & 15, wj = c >> 4, v = c & 15;
    int wrow = (t * 16 + wi * 4 + wj) * 256 + u * 16 + v;
    outv = bf2f(up[(size_t)wrow * 48 + a * 12 + b * 3 + ch]);
  } else {
    float wy[4], wx[4];
    int yb, xb;
    cubw(r, a, wy, yb);
    cubw(c, b, wx, xb);
    const float* xc = x + ch * 65536;
    float neg = 0.f;
#pragma unroll
    for (int i = 0; i < 4; ++i) {
      int yi = yb + i;
      if (yi < 0 || yi > 63) continue;
      float rowsum = 0.f;
#pragma unroll
      for (int j = 0; j < 4; ++j) {
        int xj = xb + j;
        if (xj < 0 || xj > 63) continue;
        rowsum = fmaf(wx[j], xc[(th * 64 + yi) * 256 + tw * 64 + xj], rowsum);
      }
      neg = fmaf(wy[i], rowsum, neg);
    }
    outv = neg;
  }
  sr[idx] = outv;
}

// ---------------- launcher ----------------
extern "C" void kernel_launch(void* const* d_in, const int* in_sizes, int n_in,
                              void* d_out, int out_size, void* d_ws, size_t ws_size,
                              hipStream_t stream) {
  const float* x     = (const float*)d_in[0];
  const float* gu    = (const float*)d_in[1];
  const float* s1w   = (const float*)d_in[2];
  const float* s1b   = (const float*)d_in[3];
  const float* s2w   = (const float*)d_in[4];
  const float* s2b   = (const float*)d_in[5];
  const float* s3w   = (const float*)d_in[6];
  const float* s3b   = (const float*)d_in[7];
  const float* ew    = (const float*)d_in[8];
  const float* ebias = (const float*)d_in[9];
  const float* ln1g  = (const float*)d_in[10];
  const float* ln1b  = (const float*)d_in[11];
  const float* qkvw  = (const float*)d_in[12];
  const float* qkvb  = (const float*)d_in[13];
  const float* projw = (const float*)d_in[14];
  const float* projb = (const float*)d_in[15];
  const float* ln2g  = (const float*)d_in[16];
  const float* ln2b  = (const float*)d_in[17];
  const float* mlp1w = (const float*)d_in[18];
  const float* mlp1b = (const float*)d_in[19];
  const float* mlp2w = (const float*)d_in[20];
  const float* mlp2b = (const float*)d_in[21];
  const float* upw   = (const float*)d_in[22];
  const float* upb   = (const float*)d_in[23];

  float* out = (float*)d_out;
  float* sr  = out;                 // 3*1024*1024
  float* f3o = out + 3145728;       // 16*2
  float* f2o = f3o + 32;            // 16*32
  float* f1o = f2o + 512;           // 16*64

  char* ws = (char*)d_ws;
  bf16* tok  = (bf16*)(ws);                   // 65536*180 = 23,592,960 B
  bf16* ABuf = (bf16*)(ws + 23592960);        // 65536*192 = 25,165,824 B (LN1 out, then av)
  bf16* Qp   = (bf16*)(ws + 48758784);        // 65536*192
  bf16* Kp   = (bf16*)(ws + 73924608);        // 65536*192
  bf16* Vp   = (bf16*)(ws + 99090432);        // 65536*192
  float* maskp   = (float*)(ws + 124256256);  // 64 B
  bf16* Bt_qkv  = (bf16*)(ws + 124256320);    // 576*192*2 = 221,184
  bf16* Bt_proj = (bf16*)(ws + 124477504);    // 192*192*2 = 73,728
  bf16* Bt_mlp1 = (bf16*)(ws + 124551232);    // 384*192*2 = 147,456
  bf16* Bt_mlp2 = (bf16*)(ws + 124698688);    // 192*384*2 = 147,456
  bf16* Bt_up   = (bf16*)(ws + 124846144);    // 64*192*2  = 24,576
  float* biasq  = (float*)(ws + 124870720);   // 576*4 = 2,304
  bf16* up      = (bf16*)(ws + 124873088);    // 65536*48*2 = 6,291,456
  bf16* av = ABuf;  // alias: ABuf dead after k_qkv

  k_packsel<<<1219, 256, 0, stream>>>(qkvw, projw, mlp1w, mlp2w, upw, qkvb,
                                      Bt_qkv, Bt_proj, Bt_mlp1, Bt_mlp2, Bt_up, biasq,
                                      x, gu, s1w, s1b, s2w, s2b, s3w, s3b,
                                      f1o, f2o, f3o, maskp);
  k_embed<<<16384, 256, 0, stream>>>(x, ew, ebias, ln1g, ln1b, tok, ABuf);
  k_qkv<<<1024, 256, 0, stream>>>(ABuf, Bt_qkv, biasq, Qp, Kp, Vp);
  k_attn2<<<1536, 256, 0, stream>>>(Qp, Kp, Vp, av);
  k_post<<<1024, 256, 0, stream>>>(av, tok, Bt_proj, projb, ln2g, ln2b,
                                   Bt_mlp1, mlp1b, Bt_mlp2, mlp2b, Bt_up, upb, up);
  k_blend<<<12288, 256, 0, stream>>>(up, x, maskp, sr);
}

// Round 9
// 226.823 us; speedup vs baseline: 1.9508x; 1.3045x over previous
//
#include <hip/hip_runtime.h>
#include <hip/hip_bf16.h>
#include <cstdint>

typedef __hip_bfloat16 bf16;
typedef __attribute__((ext_vector_type(8))) short short8;
typedef __attribute__((ext_vector_type(4))) short short4v;
typedef __attribute__((ext_vector_type(4))) float f32x4;
typedef __attribute__((ext_vector_type(2))) unsigned int uint2v;

__device__ __forceinline__ float bf2f(bf16 v) { return __bfloat162float(v); }
__device__ __forceinline__ bf16  f2bf(float v) { return __float2bfloat16(v); }
__device__ __forceinline__ float rbf(short s) {
  union { uint32_t u; float f; } c; c.u = ((uint32_t)(uint16_t)s) << 16; return c.f;
}
__device__ __forceinline__ uint32_t pack2(float a, float b) {
  bf16 x = f2bf(a), y = f2bf(b);
  return (uint32_t)(*(uint16_t*)&x) | ((uint32_t)(*(uint16_t*)&y) << 16);
}
__device__ __forceinline__ uint2v pack4(float a, float b, float c, float d) {
  uint2v r; r[0] = pack2(a, b); r[1] = pack2(c, d); return r;
}
// granule swizzle: XOR low-3 bits of 8-elem granule index with row&7
__device__ __forceinline__ int swz(int row, int g) { return g ^ (row & 7); }

// window-order row m -> token index (t*4096 + p)
__device__ __forceinline__ int win_to_token(int m) {
  int n = m >> 8, l = m & 255;
  int t = n >> 4, win = n & 15;
  int wi = win >> 2, wj = win & 3;
  int u = l >> 4, v = l & 15;
  return (t << 12) | ((wi * 16 + u) << 6) | (wj * 16 + v);
}

// ---------------- merged: weight packing + selector MLP ----------------
__global__ __launch_bounds__(256) void k_packsel(
    const float* __restrict__ qkvw, const float* __restrict__ projw,
    const float* __restrict__ mlp1w, const float* __restrict__ mlp2w,
    const float* __restrict__ upw, const float* __restrict__ qkvb,
    bf16* __restrict__ Bt_qkv, bf16* __restrict__ Bt_proj,
    bf16* __restrict__ Bt_mlp1, bf16* __restrict__ Bt_mlp2,
    bf16* __restrict__ Bt_up, float* __restrict__ biasq,
    const float* __restrict__ x, const float* __restrict__ gu,
    const float* __restrict__ s1w, const float* __restrict__ s1b,
    const float* __restrict__ s2w, const float* __restrict__ s2b,
    const float* __restrict__ s3w, const float* __restrict__ s3b,
    float* __restrict__ f1o, float* __restrict__ f2o, float* __restrict__ f3o,
    float* __restrict__ maskp) {
  if (blockIdx.x < 1203) {
    int idx = blockIdx.x * 256 + threadIdx.x;
    const int e0 = 576 * 192, e1 = e0 + 192 * 192, e2 = e1 + 384 * 192,
              e3 = e2 + 192 * 384, e4 = e3 + 64 * 192, e5 = e4 + 576;
    if (idx < e0) {
      int np = idx / 192, k = idx % 192;
      int buf = np / 192, colp = np % 192;
      int hd = colp >> 5, dd = colp & 31;
      float v = 0.f;
      if (dd < 30 && k < 180) v = qkvw[(size_t)k * 540 + buf * 180 + hd * 30 + dd];
      Bt_qkv[idx] = f2bf(v);
    } else if (idx < e1) {
      int off = idx - e0; int n = off / 192, kp = off % 192;
      int hd = kp >> 5, dd = kp & 31;
      float v = (dd < 30 && n < 180) ? projw[(size_t)(hd * 30 + dd) * 180 + n] : 0.f;
      Bt_proj[off] = f2bf(v);
    } else if (idx < e2) {
      int off = idx - e1; int n = off / 192, k = off % 192;
      Bt_mlp1[off] = f2bf((k < 180 && n < 360) ? mlp1w[(size_t)k * 360 + n] : 0.f);
    } else if (idx < e3) {
      int off = idx - e2; int n = off / 384, k = off % 384;
      Bt_mlp2[off] = f2bf((k < 360 && n < 180) ? mlp2w[(size_t)k * 180 + n] : 0.f);
    } else if (idx < e4) {
      int off = idx - e3; int n = off / 192, k = off % 192;
      Bt_up[off] = f2bf((k < 180 && n < 48) ? upw[(size_t)k * 48 + n] : 0.f);
    } else if (idx < e5) {
      int np = idx - e4;
      int buf = np / 192, colp = np % 192;
      int hd = colp >> 5, dd = colp & 31;
      biasq[np] = (dd < 30) ? qkvb[buf * 180 + hd * 30 + dd] : 0.f;
    }
    return;
  }
  // ---- selector (blocks 1203..1218), 256 threads ----
  int t = blockIdx.x - 1203;
  int tid = threadIdx.x;
  int th = t >> 2, tw = t & 3;
  __shared__ float pooled[192];
  __shared__ float red[256];
  __shared__ float f1s[64], f2s[32], f3s[2];
  if (tid < 192) {
    int ch = tid % 3, j = (tid / 3) & 7, i = tid / 24;
    const float* xp = x + ch * 65536 + (th * 64 + i * 8) * 256 + (tw * 64 + j * 8);
    float s = 0.f;
#pragma unroll
    for (int a = 0; a < 8; ++a)
#pragma unroll
      for (int b = 0; b < 8; ++b) s += xp[a * 256 + b];
    pooled[tid] = s * (1.0f / 64.0f);
  }
  __syncthreads();
  {
    int o = tid & 63, part = tid >> 6;
    float s = 0.f;
    for (int k = part * 48; k < part * 48 + 48; ++k) s = fmaf(pooled[k], s1w[k * 64 + o], s);
    red[tid] = s;
  }
  __syncthreads();
  if (tid < 64) {
    float v = red[tid] + red[tid + 64] + red[tid + 128] + red[tid + 192] + s1b[tid];
    f1o[t * 64 + tid] = v;
    f1s[tid] = fmaxf(v, 0.f);
  }
  __syncthreads();
  {
    int o = tid & 31, part = tid >> 5;
    float s = 0.f;
    for (int k = part * 8; k < part * 8 + 8; ++k) s = fmaf(f1s[k], s2w[k * 32 + o], s);
    red[tid] = s;
  }
  __syncthreads();
  if (tid < 32) {
    float v = s2b[tid];
#pragma unroll
    for (int p = 0; p < 8; ++p) v += red[tid + p * 32];
    f2o[t * 32 + tid] = v;
    f2s[tid] = fmaxf(v, 0.f);
  }
  __syncthreads();
  if (tid < 2) {
    float s = s3b[tid];
    for (int k = 0; k < 32; ++k) s = fmaf(f2s[k], s3w[k * 2 + tid], s);
    f3o[t * 2 + tid] = s;
    f3s[tid] = s;
  }
  __syncthreads();
  if (tid == 0) {
    float g0 = -logf(-logf(gu[t * 2 + 0] + 1e-10f) + 1e-10f);
    float g1 = -logf(-logf(gu[t * 2 + 1] + 1e-10f) + 1e-10f);
    maskp[t] = (f3s[1] + g1 > f3s[0] + g0) ? 1.0f : 0.0f;
  }
}

// ---------------- embed (3->180) + LN1 applied, outputs window-major ----------------
__global__ __launch_bounds__(256) void k_embed(
    const float* __restrict__ x, const float* __restrict__ ew,
    const float* __restrict__ eb, const float* __restrict__ g1,
    const float* __restrict__ b1, bf16* __restrict__ tok,
    bf16* __restrict__ Aq) {
  int wrow = blockIdx.x * 4 + (threadIdx.x >> 6);
  int lane = threadIdx.x & 63;
  int token = win_to_token(wrow);
  int t = token >> 12, p = token & 4095;
  int r = p >> 6, c = p & 63;
  int gh = (t >> 2) * 64 + r, gw = (t & 3) * 64 + c;
  float x0 = x[gh * 256 + gw];
  float x1 = x[65536 + gh * 256 + gw];
  float x2 = x[131072 + gh * 256 + gw];
  float v[3];
  float s = 0.f, s2 = 0.f;
#pragma unroll
  for (int i = 0; i < 3; ++i) {
    int e = lane + i * 64;
    float vv = 0.f;
    if (e < 180) {
      vv = eb[e];
      vv = fmaf(x0, ew[e], vv);
      vv = fmaf(x1, ew[180 + e], vv);
      vv = fmaf(x2, ew[360 + e], vv);
      tok[(size_t)wrow * 180 + e] = f2bf(vv);
      s += vv; s2 = fmaf(vv, vv, s2);
    }
    v[i] = vv;
  }
#pragma unroll
  for (int off = 32; off; off >>= 1) { s += __shfl_xor(s, off); s2 += __shfl_xor(s2, off); }
  float mu = s * (1.f / 180.f);
  float rs = rsqrtf(s2 * (1.f / 180.f) - mu * mu + 1e-5f);
#pragma unroll
  for (int i = 0; i < 3; ++i) {
    int e = lane + i * 64;
    if (e < 192) {
      float a = (e < 180) ? ((v[i] - mu) * rs * g1[e] + b1[e]) : 0.f;
      Aq[(size_t)wrow * 192 + e] = f2bf(a);
    }
  }
}

// ---------------- qkv GEMM: LDS double-buffered B, swizzled; 8B coalesced stores ------
// 128 rows/block; wave owns 32 rows (2 x 16-row frags). One barrier per n-tile.
__global__ __launch_bounds__(256) void k_qkv2(
    const bf16* __restrict__ A, const bf16* __restrict__ Bt,
    const float* __restrict__ biasq, bf16* __restrict__ Qp,
    bf16* __restrict__ Kp, bf16* __restrict__ Vp) {
  __shared__ bf16 Bs[2][64 * 192];
  const int tid = threadIdx.x;
  const int w = tid >> 6, l = tid & 63;
  const int lr = l & 15, lk = l >> 4;
  const int rbase = blockIdx.x * 128 + w * 32 + lr;

  // A-fragments in registers, read once
  short8 fa[2][6];
#pragma unroll
  for (int i = 0; i < 2; ++i) {
    const bf16* Ab = A + (size_t)(rbase + i * 16) * 192 + lk * 8;
#pragma unroll
    for (int ks = 0; ks < 6; ++ks) fa[i][ks] = *(const short8*)(Ab + ks * 32);
  }

  // stage n-tile 0 into buf 0
  {
    const bf16* src = Bt;
#pragma unroll
    for (int it = 0; it < 6; ++it) {
      int c = tid + it * 256;
      int n = c / 24, g = c % 24;
      *(short8*)&Bs[0][n * 192 + swz(n, g) * 8] = *(const short8*)(src + n * 192 + g * 8);
    }
  }

  for (int nt = 0; nt < 9; ++nt) {
    __syncthreads();  // staged buf (nt&1) ready; all waves done with buf ((nt+1)&1)
    if (nt < 8) {
      const bf16* src = Bt + (size_t)(nt + 1) * 64 * 192;
      bf16* dstb = Bs[(nt + 1) & 1];
#pragma unroll
      for (int it = 0; it < 6; ++it) {
        int c = tid + it * 256;
        int n = c / 24, g = c % 24;
        *(short8*)&dstb[n * 192 + swz(n, g) * 8] = *(const short8*)(src + n * 192 + g * 8);
      }
    }
    const bf16* Bb = Bs[nt & 1];
    f32x4 acc[2][4];
#pragma unroll
    for (int i = 0; i < 2; ++i)
#pragma unroll
      for (int j = 0; j < 4; ++j) acc[i][j] = (f32x4){0.f, 0.f, 0.f, 0.f};
#pragma unroll
    for (int ks = 0; ks < 6; ++ks) {
      short8 fb[4];
#pragma unroll
      for (int j = 0; j < 4; ++j) {
        int rn = j * 16 + lr;
        fb[j] = *(const short8*)&Bb[rn * 192 + swz(rn, ks * 4 + lk) * 8];
      }
#pragma unroll
      for (int i = 0; i < 2; ++i)
#pragma unroll
        for (int j = 0; j < 4; ++j)
          acc[i][j] = __builtin_amdgcn_mfma_f32_16x16x32_bf16(fb[j], fa[i][ks], acc[i][j], 0, 0, 0);
    }
    bf16* dst = (nt < 3) ? Qp : (nt < 6) ? Kp : Vp;
    int c0 = (nt % 3) * 64;
#pragma unroll
    for (int i = 0; i < 2; ++i) {
      int row = rbase + i * 16;
#pragma unroll
      for (int j = 0; j < 4; ++j) {
        int np = nt * 64 + j * 16 + lk * 4;
        f32x4 bv = *(const f32x4*)&biasq[np];
        *(uint2v*)(dst + (size_t)row * 192 + c0 + j * 16 + lk * 4) =
            pack4(acc[i][j][0] + bv[0], acc[i][j][1] + bv[1],
                  acc[i][j][2] + bv[2], acc[i][j][3] + bv[3]);
      }
    }
  }
}

// ---------------- MFMA attention: block = (window, head), swapped PV ----------------
__global__ __launch_bounds__(256) void k_attn2(
    const bf16* __restrict__ Qp, const bf16* __restrict__ Kp,
    const bf16* __restrict__ Vp, bf16* __restrict__ av) {
  const int blk = blockIdx.x;
  const int win = blk / 6, hd = blk % 6;
  const int tid = threadIdx.x;
  const int w = tid >> 6, l = tid & 63;
  const int lr = l & 15, lk = l >> 4;
  const float scale = 0.18257418583505536f;  // 1/sqrt(30)

  __shared__ bf16 Ks[256][40];
  __shared__ bf16 Vs[32][264];
  __shared__ bf16 Ps[4][16][264];

  {  // stage K rows
    const bf16* src = Kp + (size_t)(win * 256 + tid) * 192 + hd * 32;
#pragma unroll
    for (int c = 0; c < 4; ++c)
      *(short8*)&Ks[tid][c * 8] = *(const short8*)(src + c * 8);
  }
  {  // stage V rows -> transposed Vs[d][key]
    const bf16* src = Vp + (size_t)(win * 256 + tid) * 192 + hd * 32;
    short8 vv[4];
#pragma unroll
    for (int c = 0; c < 4; ++c) vv[c] = *(const short8*)(src + c * 8);
#pragma unroll
    for (int c = 0; c < 4; ++c)
#pragma unroll
      for (int e = 0; e < 8; ++e)
        *(short*)&Vs[c * 8 + e][tid] = vv[c][e];
  }
  __syncthreads();

  for (int qt = 0; qt < 4; ++qt) {
    const int qbase = qt * 64 + w * 16;
    short8 fq = *(const short8*)(Qp + (size_t)(win * 256 + qbase + lr) * 192 + hd * 32 + lk * 8);
    f32x4 accS[16];
#pragma unroll
    for (int kt = 0; kt < 16; ++kt) {
      short8 fk = *(const short8*)(&Ks[kt * 16 + lr][lk * 8]);
      accS[kt] = __builtin_amdgcn_mfma_f32_16x16x32_bf16(
          fk, fq, (f32x4){0.f, 0.f, 0.f, 0.f}, 0, 0, 0);
    }
    float mraw = -1e30f;
#pragma unroll
    for (int kt = 0; kt < 16; ++kt)
#pragma unroll
      for (int r = 0; r < 4; ++r) mraw = fmaxf(mraw, accS[kt][r]);
    mraw = fmaxf(mraw, __shfl_xor(mraw, 16));
    mraw = fmaxf(mraw, __shfl_xor(mraw, 32));
    const float mc = mraw * scale;
    float lsum = 0.f;
#pragma unroll
    for (int kt = 0; kt < 16; ++kt) {
      float p0 = __expf(fmaf(accS[kt][0], scale, -mc));
      float p1 = __expf(fmaf(accS[kt][1], scale, -mc));
      float p2 = __expf(fmaf(accS[kt][2], scale, -mc));
      float p3 = __expf(fmaf(accS[kt][3], scale, -mc));
      lsum += (p0 + p1) + (p2 + p3);
      *(uint32_t*)&Ps[w][lr][kt * 16 + lk * 4]     = pack2(p0, p1);
      *(uint32_t*)&Ps[w][lr][kt * 16 + lk * 4 + 2] = pack2(p2, p3);
    }
    lsum += __shfl_xor(lsum, 16);
    lsum += __shfl_xor(lsum, 32);
    __syncthreads();
    f32x4 accO0 = (f32x4){0.f, 0.f, 0.f, 0.f};
    f32x4 accO1 = (f32x4){0.f, 0.f, 0.f, 0.f};
#pragma unroll
    for (int ks = 0; ks < 8; ++ks) {
      short8 fp  = *(const short8*)(&Ps[w][lr][ks * 32 + lk * 8]);
      short8 fv0 = *(const short8*)(&Vs[lr][ks * 32 + lk * 8]);
      short8 fv1 = *(const short8*)(&Vs[16 + lr][ks * 32 + lk * 8]);
      accO0 = __builtin_amdgcn_mfma_f32_16x16x32_bf16(fv0, fp, accO0, 0, 0, 0);
      accO1 = __builtin_amdgcn_mfma_f32_16x16x32_bf16(fv1, fp, accO1, 0, 0, 0);
    }
    float invl = 1.f / lsum;
    bf16* avrow = av + (size_t)(win * 256 + qbase + lr) * 192 + hd * 32;
    *(uint2v*)(avrow + lk * 4) =
        pack4(accO0[0] * invl, accO0[1] * invl, accO0[2] * invl, accO0[3] * invl);
    *(uint2v*)(avrow + 16 + lk * 4) =
        pack4(accO1[0] * invl, accO1[1] * invl, accO1[2] * invl, accO1[3] * invl);
    __syncthreads();
  }
}

// ---------------- fused post-attn: proj+res -> LN2 -> mlp1(gelu)⊕mlp2+res -> up ----
__global__ __launch_bounds__(256) void k_post(
    const bf16* __restrict__ av, const bf16* __restrict__ tok,
    const bf16* __restrict__ Btp, const float* __restrict__ pb,
    const float* __restrict__ g2, const float* __restrict__ b2,
    const bf16* __restrict__ Bt1, const float* __restrict__ b1m,
    const bf16* __restrict__ Bt2, const float* __restrict__ b2m,
    const bf16* __restrict__ Btu, const float* __restrict__ bu,
    bf16* __restrict__ up) {
  __shared__ bf16 Bs[64 * 192];
  __shared__ bf16 T2[64 * 192];
  __shared__ bf16 Hm[64 * 192];
  const int tid = threadIdx.x;
  const int w = tid >> 6, l = tid & 63;
  const int lr = l & 15, lk = l >> 4;
  const int row_l = w * 16 + lr;
  const int row_g = blockIdx.x * 64 + row_l;
  const int half = (lk & 1) * 4;

  short8 fa[6];
  {
    const bf16* ab = av + (size_t)row_g * 192 + lk * 8;
#pragma unroll
    for (int ks = 0; ks < 6; ++ks) fa[ks] = *(const short8*)(ab + ks * 32);
  }

  f32x4 t2v[3][4];
#pragma unroll
  for (int nt = 0; nt < 3; ++nt) {
    __syncthreads();
    for (int c = tid; c < 1536; c += 256) {
      int n = c / 24, g = c % 24;
      *(short8*)&Bs[n * 192 + swz(n, g) * 8] =
          *(const short8*)(Btp + (size_t)(nt * 64 + n) * 192 + g * 8);
    }
    __syncthreads();
    f32x4 acc[4];
#pragma unroll
    for (int j = 0; j < 4; ++j) acc[j] = (f32x4){0.f, 0.f, 0.f, 0.f};
#pragma unroll
    for (int ks = 0; ks < 6; ++ks) {
      short8 fb[4];
#pragma unroll
      for (int j = 0; j < 4; ++j) {
        int rn = j * 16 + lr;
        fb[j] = *(const short8*)&Bs[rn * 192 + swz(rn, ks * 4 + lk) * 8];
      }
#pragma unroll
      for (int j = 0; j < 4; ++j)
        acc[j] = __builtin_amdgcn_mfma_f32_16x16x32_bf16(fb[j], fa[ks], acc[j], 0, 0, 0);
    }
#pragma unroll
    for (int j = 0; j < 4; ++j) {
      int n = nt * 64 + j * 16 + lk * 4;
      if (n < 180) {
        f32x4 bv = *(const f32x4*)&pb[n];
        short4v tv = *(const short4v*)(tok + (size_t)row_g * 180 + n);
#pragma unroll
        for (int q = 0; q < 4; ++q) t2v[nt][j][q] = acc[j][q] + bv[q] + rbf(tv[q]);
      } else {
        t2v[nt][j] = (f32x4){0.f, 0.f, 0.f, 0.f};
      }
    }
  }

  {
    float s = 0.f, s2 = 0.f;
#pragma unroll
    for (int nt = 0; nt < 3; ++nt)
#pragma unroll
      for (int j = 0; j < 4; ++j)
#pragma unroll
        for (int q = 0; q < 4; ++q) { float v = t2v[nt][j][q]; s += v; s2 = fmaf(v, v, s2); }
    s += __shfl_xor(s, 16);  s += __shfl_xor(s, 32);
    s2 += __shfl_xor(s2, 16); s2 += __shfl_xor(s2, 32);
    float mu = s * (1.f / 180.f);
    float rs = rsqrtf(s2 * (1.f / 180.f) - mu * mu + 1e-5f);
#pragma unroll
    for (int nt = 0; nt < 3; ++nt)
#pragma unroll
      for (int j = 0; j < 4; ++j) {
        int n = nt * 64 + j * 16 + lk * 4;
        float h[4] = {0.f, 0.f, 0.f, 0.f};
        if (n < 180) {
          f32x4 gv = *(const f32x4*)&g2[n];
          f32x4 bv = *(const f32x4*)&b2[n];
#pragma unroll
          for (int q = 0; q < 4; ++q) h[q] = (t2v[nt][j][q] - mu) * rs * gv[q] + bv[q];
        }
        int g = nt * 8 + j * 2 + (lk >> 1);
        *(uint2v*)&Hm[row_l * 192 + swz(row_l, g) * 8 + half] = pack4(h[0], h[1], h[2], h[3]);
      }
  }
  __syncthreads();
  short8 fh[6];
#pragma unroll
  for (int ks = 0; ks < 6; ++ks)
    fh[ks] = *(const short8*)&Hm[row_l * 192 + swz(row_l, ks * 4 + lk) * 8];

  f32x4 acc2[3][4];
#pragma unroll
  for (int t = 0; t < 3; ++t)
#pragma unroll
    for (int j = 0; j < 4; ++j) acc2[t][j] = (f32x4){0.f, 0.f, 0.f, 0.f};
#pragma unroll
  for (int nt = 0; nt < 6; ++nt) {
    __syncthreads();
    for (int c = tid; c < 1536; c += 256) {
      int n = c / 24, g = c % 24;
      *(short8*)&Bs[n * 192 + swz(n, g) * 8] =
          *(const short8*)(Bt1 + (size_t)(nt * 64 + n) * 192 + g * 8);
    }
    __syncthreads();
    f32x4 acc1[4];
#pragma unroll
    for (int j = 0; j < 4; ++j) acc1[j] = (f32x4){0.f, 0.f, 0.f, 0.f};
#pragma unroll
    for (int ks = 0; ks < 6; ++ks) {
      short8 fb[4];
#pragma unroll
      for (int j = 0; j < 4; ++j) {
        int rn = j * 16 + lr;
        fb[j] = *(const short8*)&Bs[rn * 192 + swz(rn, ks * 4 + lk) * 8];
      }
#pragma unroll
      for (int j = 0; j < 4; ++j)
        acc1[j] = __builtin_amdgcn_mfma_f32_16x16x32_bf16(fb[j], fh[ks], acc1[j], 0, 0, 0);
    }
#pragma unroll
    for (int j = 0; j < 4; ++j) {
      int n = nt * 64 + j * 16 + lk * 4;
      float m4[4] = {0.f, 0.f, 0.f, 0.f};
      if (n < 360) {
        f32x4 bv = *(const f32x4*)&b1m[n];
#pragma unroll
        for (int q = 0; q < 4; ++q) {
          float v = acc1[j][q] + bv[q];
          float u = 0.7978845608028654f * (v + 0.044715f * v * v * v);
          m4[q] = v / (1.f + __expf(-2.f * u));
        }
      }
      int g = j * 2 + (lk >> 1);
      *(uint2v*)&Hm[row_l * 192 + swz(row_l, g) * 8 + half] = pack4(m4[0], m4[1], m4[2], m4[3]);
    }
    __syncthreads();
    for (int c = tid; c < 1536; c += 256) {
      int n = c / 8, g = c % 8;
      *(short8*)&Bs[n * 64 + swz(n, g) * 8] =
          *(const short8*)(Bt2 + (size_t)n * 384 + nt * 64 + g * 8);
    }
    __syncthreads();
    short8 fm[2];
#pragma unroll
    for (int s = 0; s < 2; ++s)
      fm[s] = *(const short8*)&Hm[row_l * 192 + swz(row_l, s * 4 + lk) * 8];
#pragma unroll
    for (int s = 0; s < 2; ++s)
#pragma unroll
      for (int t = 0; t < 3; ++t)
#pragma unroll
        for (int j = 0; j < 4; ++j) {
          int rn = t * 64 + j * 16 + lr;
          short8 fb2 = *(const short8*)&Bs[rn * 64 + swz(rn, s * 4 + lk) * 8];
          acc2[t][j] = __builtin_amdgcn_mfma_f32_16x16x32_bf16(fb2, fm[s], acc2[t][j], 0, 0, 0);
        }
  }

#pragma unroll
  for (int t = 0; t < 3; ++t)
#pragma unroll
    for (int j = 0; j < 4; ++j) {
      int n = t * 64 + j * 16 + lk * 4;
      float o4[4] = {0.f, 0.f, 0.f, 0.f};
      if (n < 180) {
        f32x4 bv = *(const f32x4*)&b2m[n];
#pragma unroll
        for (int q = 0; q < 4; ++q) o4[q] = acc2[t][j][q] + bv[q] + t2v[t][j][q];
      }
      int g = t * 8 + j * 2 + (lk >> 1);
      *(uint2v*)&T2[row_l * 192 + swz(row_l, g) * 8 + half] = pack4(o4[0], o4[1], o4[2], o4[3]);
    }
  __syncthreads();

  for (int c = tid; c < 1536; c += 256) {
    int n = c / 24, g = c % 24;
    *(short8*)&Bs[n * 192 + swz(n, g) * 8] =
        *(const short8*)(Btu + (size_t)n * 192 + g * 8);
  }
  __syncthreads();
  short8 ft[6];
#pragma unroll
  for (int ks = 0; ks < 6; ++ks)
    ft[ks] = *(const short8*)&T2[row_l * 192 + swz(row_l, ks * 4 + lk) * 8];
  f32x4 acc3[3];
#pragma unroll
  for (int j = 0; j < 3; ++j) acc3[j] = (f32x4){0.f, 0.f, 0.f, 0.f};
#pragma unroll
  for (int ks = 0; ks < 6; ++ks) {
    short8 fb[3];
#pragma unroll
    for (int j = 0; j < 3; ++j) {
      int rn = j * 16 + lr;
      fb[j] = *(const short8*)&Bs[rn * 192 + swz(rn, ks * 4 + lk) * 8];
    }
#pragma unroll
    for (int j = 0; j < 3; ++j)
      acc3[j] = __builtin_amdgcn_mfma_f32_16x16x32_bf16(fb[j], ft[ks], acc3[j], 0, 0, 0);
  }
#pragma unroll
  for (int j = 0; j < 3; ++j) {
    int n = j * 16 + lk * 4;
    f32x4 bv = *(const f32x4*)&bu[n];
    *(uint2v*)(up + (size_t)row_g * 48 + n) =
        pack4(acc3[j][0] + bv[0], acc3[j][1] + bv[1], acc3[j][2] + bv[2], acc3[j][3] + bv[3]);
  }
}

// ---------------- bicubic weights (jax Keys a=-0.5, half-pixel, edge renorm) ----------------
__device__ const float c_cubw[4][4] = {
    {-0.0439453125f, 0.3896484375f, 0.7275390625f, -0.0732421875f},
    {-0.0068359375f, 0.0908203125f, 0.9638671875f, -0.0478515625f},
    {-0.0478515625f, 0.9638671875f, 0.0908203125f, -0.0068359375f},
    {-0.0732421875f, 0.7275390625f, 0.3896484375f, -0.0439453125f},
};

__device__ __forceinline__ void cubw(int r, int ph, float* w, int& base) {
  base = r + ((ph < 2) ? -2 : -1);
  float sum = 0.f;
#pragma unroll
  for (int i = 0; i < 4; ++i) {
    int idx = base + i;
    float wi = (idx >= 0 && idx < 64) ? c_cubw[ph][i] : 0.f;
    w[i] = wi; sum += wi;
  }
  float inv = 1.f / sum;
#pragma unroll
  for (int i = 0; i < 4; ++i) w[i] *= inv;
}

// ---------------- blend: pixel-shuffle of up + bicubic + mask blend ----------------
__global__ __launch_bounds__(256) void k_blend(
    const bf16* __restrict__ up, const float* __restrict__ x,
    const float* __restrict__ maskp, float* __restrict__ sr) {
  int idx = blockIdx.x * 256 + threadIdx.x;
  int ch = idx >> 20;
  int rem = idx & 1048575;
  int gR = rem >> 10, gC = rem & 1023;
  int th = gR >> 8, tw = gC >> 8;
  int t = th * 4 + tw;
  int R = gR & 255, C = gC & 255;
  int r = R >> 2, a = R & 3, c = C >> 2, b = C & 3;
  float m = maskp[t];
  float outv;
  if (m > 0.5f) {
    int wi = r >> 4, u = r & 15, wj = c >> 4, v = c & 15;
    int wrow = (t * 16 + wi * 4 + wj) * 256 + u * 16 + v;
    outv = bf2f(up[(size_t)wrow * 48 + a * 12 + b * 3 + ch]);
  } else {
    float wy[4], wx[4];
    int yb, xb;
    cubw(r, a, wy, yb);
    cubw(c, b, wx, xb);
    const float* xc = x + ch * 65536;
    float neg = 0.f;
#pragma unroll
    for (int i = 0; i < 4; ++i) {
      int yi = yb + i;
      if (yi < 0 || yi > 63) continue;
      float rowsum = 0.f;
#pragma unroll
      for (int j = 0; j < 4; ++j) {
        int xj = xb + j;
        if (xj < 0 || xj > 63) continue;
        rowsum = fmaf(wx[j], xc[(th * 64 + yi) * 256 + tw * 64 + xj], rowsum);
      }
      neg = fmaf(wy[i], rowsum, neg);
    }
    outv = neg;
  }
  sr[idx] = outv;
}

// ---------------- launcher ----------------
extern "C" void kernel_launch(void* const* d_in, const int* in_sizes, int n_in,
                              void* d_out, int out_size, void* d_ws, size_t ws_size,
                              hipStream_t stream) {
  const float* x     = (const float*)d_in[0];
  const float* gu    = (const float*)d_in[1];
  const float* s1w   = (const float*)d_in[2];
  const float* s1b   = (const float*)d_in[3];
  const float* s2w   = (const float*)d_in[4];
  const float* s2b   = (const float*)d_in[5];
  const float* s3w   = (const float*)d_in[6];
  const float* s3b   = (const float*)d_in[7];
  const float* ew    = (const float*)d_in[8];
  const float* ebias = (const float*)d_in[9];
  const float* ln1g  = (const float*)d_in[10];
  const float* ln1b  = (const float*)d_in[11];
  const float* qkvw  = (const float*)d_in[12];
  const float* qkvb  = (const float*)d_in[13];
  const float* projw = (const float*)d_in[14];
  const float* projb = (const float*)d_in[15];
  const float* ln2g  = (const float*)d_in[16];
  const float* ln2b  = (const float*)d_in[17];
  const float* mlp1w = (const float*)d_in[18];
  const float* mlp1b = (const float*)d_in[19];
  const float* mlp2w = (const float*)d_in[20];
  const float* mlp2b = (const float*)d_in[21];
  const float* upw   = (const float*)d_in[22];
  const float* upb   = (const float*)d_in[23];

  float* out = (float*)d_out;
  float* sr  = out;                 // 3*1024*1024
  float* f3o = out + 3145728;       // 16*2
  float* f2o = f3o + 32;            // 16*32
  float* f1o = f2o + 512;           // 16*64

  char* ws = (char*)d_ws;
  bf16* tok  = (bf16*)(ws);                   // 65536*180 = 23,592,960 B
  bf16* ABuf = (bf16*)(ws + 23592960);        // 65536*192 = 25,165,824 B (LN1 out, then av)
  bf16* Qp   = (bf16*)(ws + 48758784);        // 65536*192
  bf16* Kp   = (bf16*)(ws + 73924608);        // 65536*192
  bf16* Vp   = (bf16*)(ws + 99090432);        // 65536*192
  float* maskp   = (float*)(ws + 124256256);  // 64 B
  bf16* Bt_qkv  = (bf16*)(ws + 124256320);    // 576*192*2 = 221,184
  bf16* Bt_proj = (bf16*)(ws + 124477504);    // 192*192*2 = 73,728
  bf16* Bt_mlp1 = (bf16*)(ws + 124551232);    // 384*192*2 = 147,456
  bf16* Bt_mlp2 = (bf16*)(ws + 124698688);    // 192*384*2 = 147,456
  bf16* Bt_up   = (bf16*)(ws + 124846144);    // 64*192*2  = 24,576
  float* biasq  = (float*)(ws + 124870720);   // 576*4 = 2,304
  bf16* up      = (bf16*)(ws + 124873088);    // 65536*48*2 = 6,291,456
  bf16* av = ABuf;  // alias: ABuf dead after k_qkv2

  k_packsel<<<1219, 256, 0, stream>>>(qkvw, projw, mlp1w, mlp2w, upw, qkvb,
                                      Bt_qkv, Bt_proj, Bt_mlp1, Bt_mlp2, Bt_up, biasq,
                                      x, gu, s1w, s1b, s2w, s2b, s3w, s3b,
                                      f1o, f2o, f3o, maskp);
  k_embed<<<16384, 256, 0, stream>>>(x, ew, ebias, ln1g, ln1b, tok, ABuf);
  k_qkv2<<<512, 256, 0, stream>>>(ABuf, Bt_qkv, biasq, Qp, Kp, Vp);
  k_attn2<<<1536, 256, 0, stream>>>(Qp, Kp, Vp, av);
  k_post<<<1024, 256, 0, stream>>>(av, tok, Bt_proj, projb, ln2g, ln2b,
                                   Bt_mlp1, mlp1b, Bt_mlp2, mlp2b, Bt_up, upb, up);
  k_blend<<<12288, 256, 0, stream>>>(up, x, maskp, sr);
}